// Round 3
// baseline (3546.661 us; speedup 1.0000x reference)
//
#include <hip/hip_runtime.h>
#include <cstdint>

// Round 6: gather MLP doubled. Profile (R2) showed xg_convgather is top kernel
// (3 x 230us, VALU 33%, HBM 15%, occ 82% -> latency-bound, only 4 loads in flight).
// - xg_gather1 / xg_convgather: 8 CSR rows per wave (8 independent load streams)
// - next-iteration col[] index loads issued before FMA consume (SW pipeline)
// GEMM unchanged from Round-4/5 (float4 A-fragments, K batched x4).

#define CUTOFF 5.0f
#define PI_F 3.14159265358979323846f

__device__ __forceinline__ float siluf(float v){ float s=1.f/(1.f+__expf(-v)); return v*s; }
__device__ __forceinline__ float silud(float v){ float s=1.f/(1.f+__expf(-v)); return s*(1.f+v*(1.f-s)); }

// ---- DPP wave64 sum: result valid in lane 63 (VALU pipe, no LDS traffic)
template<int CTRL>
__device__ __forceinline__ float dpp_radd(float x){
  int y = __builtin_amdgcn_update_dpp(0, __float_as_int(x), CTRL, 0xf, 0xf, false);
  return x + __int_as_float(y);
}
__device__ __forceinline__ float wave_sum63(float x){
  x = dpp_radd<0x111>(x);  // row_shr:1
  x = dpp_radd<0x112>(x);  // row_shr:2
  x = dpp_radd<0x114>(x);  // row_shr:4
  x = dpp_radd<0x118>(x);  // row_shr:8
  x = dpp_radd<0x142>(x);  // row_bcast:15
  x = dpp_radd<0x143>(x);  // row_bcast:31 -> lane63 has full sum
  return x;
}

constexpr int PRE_NONE=0, PRE_SCALE_ROW=1, PRE_SILU=2, PRE_MUL_SILUD=3;
constexpr int POST_PLAIN=0, POST_BIAS=1, POST_GATE=2, POST_X0=3, POST_CONV=4, POST_MUL_SILUD=5;

// ---------------------------------------------------------------- GEMM
template<int PRE, int POST, bool BT>
__global__ __launch_bounds__(256) void xg_gemm(
    const float* __restrict__ A, int ldA, int K,
    const float* __restrict__ B, int ldB, int N,
    float* __restrict__ C, int ldC,
    const float* __restrict__ rowscale,   // PRE_SCALE_ROW
    const float* __restrict__ auxA,       // PRE_MUL_SILUD  (ld 128)
    const float* __restrict__ auxC,       // POST_CONV / POST_GATE (x_l) / POST_MUL_SILUD (h_pre)
    const float* __restrict__ bias,       // POST_BIAS / POST_X0
    const float* __restrict__ l8g,        // POST_X0 (E x 8 row-major)
    const float* __restrict__ Wvsg,       // POST_X0 (8 x 128)
    float* __restrict__ C2,               // POST_CONV x_{l+1}
    int E)
{
  __shared__ float Alds[64][36];          // 36-float row stride: 144B, 16B aligned
  __shared__ float Blds[32][132];
  __shared__ float l8s[8][64];
  __shared__ float WvsS[8][128];

  const int tid = threadIdx.x;
  const int e0 = blockIdx.x*64;
  const int n0 = blockIdx.y*128;

  if constexpr (POST==POST_X0) {
    for (int i=tid;i<1024;i+=256) WvsS[i>>7][i&127] = Wvsg[i];
    for (int i=tid;i<512;i+=256) {
      int r=i>>3, c=i&7; int e=e0+r;
      l8s[c][r] = (e<E)? l8g[(size_t)e*8+c] : 0.f;
    }
  }

  const int ty = tid>>5, tx = tid&31;
  float acc[8][4];
  #pragma unroll
  for (int i=0;i<8;i++){acc[i][0]=0.f;acc[i][1]=0.f;acc[i][2]=0.f;acc[i][3]=0.f;}

  for (int k0=0;k0<K;k0+=32) {
    __syncthreads();
    { // A tile 64x32
      const int kk = tid&31, rb = tid>>5;
      #pragma unroll
      for (int p=0;p<8;p++) {
        int r = rb + p*8;
        int e = e0+r, k = k0+kk;
        float v = 0.f;
        if (e<E && k<K) {
          v = A[(size_t)e*ldA + k];
          if constexpr (PRE==PRE_SCALE_ROW) v *= rowscale[e];
          if constexpr (PRE==PRE_SILU)      v = siluf(v);
          if constexpr (PRE==PRE_MUL_SILUD) v *= silud(auxA[(size_t)e*128+k]);
        }
        Alds[r][kk] = v;
      }
    }
    if constexpr (!BT) { // B row-major KxN
      const int n = tid&127, kb = tid>>7;
      #pragma unroll
      for (int p=0;p<16;p++) {
        int kk = kb + p*2;
        int k = k0+kk, nn = n0+n;
        Blds[kk][n] = (k<K && nn<N) ? B[(size_t)k*ldB+nn] : 0.f;
      }
    } else {             // B = W^T, W row-major NxK (ldB)
      const int kk = tid&31, nb = tid>>5;
      #pragma unroll
      for (int p=0;p<16;p++) {
        int n = nb + p*8;
        int k = k0+kk, nn = n0+n;
        Blds[kk][n] = (k<K && nn<N) ? B[(size_t)nn*ldB+k] : 0.f;
      }
    }
    __syncthreads();
    #pragma unroll
    for (int kk4=0;kk4<8;kk4++) {
      float4 b0 = *(const float4*)&Blds[kk4*4+0][tx*4];
      float4 b1 = *(const float4*)&Blds[kk4*4+1][tx*4];
      float4 b2 = *(const float4*)&Blds[kk4*4+2][tx*4];
      float4 b3 = *(const float4*)&Blds[kk4*4+3][tx*4];
      #pragma unroll
      for (int i=0;i<8;i++) {
        float4 a = *(const float4*)&Alds[ty*8+i][kk4*4];
        acc[i][0] = fmaf(a.x,b0.x,acc[i][0]);
        acc[i][1] = fmaf(a.x,b0.y,acc[i][1]);
        acc[i][2] = fmaf(a.x,b0.z,acc[i][2]);
        acc[i][3] = fmaf(a.x,b0.w,acc[i][3]);
        acc[i][0] = fmaf(a.y,b1.x,acc[i][0]);
        acc[i][1] = fmaf(a.y,b1.y,acc[i][1]);
        acc[i][2] = fmaf(a.y,b1.z,acc[i][2]);
        acc[i][3] = fmaf(a.y,b1.w,acc[i][3]);
        acc[i][0] = fmaf(a.z,b2.x,acc[i][0]);
        acc[i][1] = fmaf(a.z,b2.y,acc[i][1]);
        acc[i][2] = fmaf(a.z,b2.z,acc[i][2]);
        acc[i][3] = fmaf(a.z,b2.w,acc[i][3]);
        acc[i][0] = fmaf(a.w,b3.x,acc[i][0]);
        acc[i][1] = fmaf(a.w,b3.y,acc[i][1]);
        acc[i][2] = fmaf(a.w,b3.z,acc[i][2]);
        acc[i][3] = fmaf(a.w,b3.w,acc[i][3]);
      }
    }
  }

  const int cbase = n0 + tx*4;
  #pragma unroll
  for (int i=0;i<8;i++) {
    int e = e0 + ty*8 + i;
    if (e>=E) break;
    size_t ci = (size_t)e*ldC + cbase;
    float4 v = make_float4(acc[i][0],acc[i][1],acc[i][2],acc[i][3]);
    if constexpr (POST==POST_BIAS) {
      v.x+=bias[cbase]; v.y+=bias[cbase+1]; v.z+=bias[cbase+2]; v.w+=bias[cbase+3];
      *(float4*)&C[ci]=v;
    } else if constexpr (POST==POST_GATE) { // m = silu(acc) * x_l
      float4 xl4 = *(const float4*)&auxC[(size_t)e*128 + cbase];
      v.x=siluf(v.x)*xl4.x; v.y=siluf(v.y)*xl4.y;
      v.z=siluf(v.z)*xl4.z; v.w=siluf(v.w)*xl4.w;
      *(float4*)&C[ci]=v;
    } else if constexpr (POST==POST_X0) {
      float vp0=0.f,vp1=0.f,vp2=0.f,vp3=0.f;
      int r = ty*8+i;
      #pragma unroll
      for (int c=0;c<8;c++){
        float lc = l8s[c][r];
        vp0=fmaf(lc,WvsS[c][cbase+0],vp0); vp1=fmaf(lc,WvsS[c][cbase+1],vp1);
        vp2=fmaf(lc,WvsS[c][cbase+2],vp2); vp3=fmaf(lc,WvsS[c][cbase+3],vp3);
      }
      v.x += bias[cbase+0] + siluf(vp0);
      v.y += bias[cbase+1] + siluf(vp1);
      v.z += bias[cbase+2] + siluf(vp2);
      v.w += bias[cbase+3] + siluf(vp3);
      *(float4*)&C[ci]=v;
    } else if constexpr (POST==POST_CONV) {
      *(float4*)&C[ci]=v; // apre_l
      float4 xl = *(const float4*)&auxC[(size_t)e*128 + cbase];
      float4 o = make_float4(xl.x+siluf(v.x), xl.y+siluf(v.y),
                             xl.z+siluf(v.z), xl.w+siluf(v.w));
      *(float4*)&C2[ci]=o; // x_{l+1}
    } else if constexpr (POST==POST_MUL_SILUD) {
      float4 a4 = *(const float4*)&auxC[(size_t)e*128 + cbase];
      v.x*=silud(a4.x); v.y*=silud(a4.y); v.z*=silud(a4.z); v.w*=silud(a4.w);
      *(float4*)&C[ci]=v;
    } else { // POST_PLAIN
      if (cbase+3 < N) { *(float4*)&C[ci]=v; }
      else {
        float vv[4]={v.x,v.y,v.z,v.w};
        #pragma unroll
        for (int j=0;j<4;j++) if (cbase+j<N) C[ci+j]=vv[j];
      }
    }
  }
}

// ---------------------------------------------------------------- geometry
__global__ __launch_bounds__(256) void xg_geom(const float* __restrict__ pos,
  const int* __restrict__ eidx, int E,
  float* __restrict__ bv, float* __restrict__ d_a, float* __restrict__ env_a,
  float* __restrict__ l8, float* __restrict__ rbf)
{
  int e = blockIdx.x*256+threadIdx.x;
  if (e>=E) return;
  int s = eidx[e], t = eidx[E+e];
  float bx = pos[s*3+0]-pos[t*3+0];
  float by = pos[s*3+1]-pos[t*3+1];
  float bz = pos[s*3+2]-pos[t*3+2];
  float d = sqrtf(bx*bx+by*by+bz*bz + 1e-12f);
  bv[(size_t)e*3+0]=bx; bv[(size_t)e*3+1]=by; bv[(size_t)e*3+2]=bz;
  d_a[e]=d;
  float xx = d/CUTOFF;
  float x2=xx*xx, x4=x2*x2, x5=x4*xx, x6=x5*xx, x7=x6*xx;
  env_a[e] = (d<CUTOFF)? (1.f-21.f*x5+35.f*x6-15.f*x7) : 0.f;
  float inv = 1.f/d;
  float ux=bx*inv, uy=by*inv, uz=bz*inv;
  const float s3 = 1.7320508075688772f;
  size_t b8=(size_t)e*8;
  l8[b8+0]=uy; l8[b8+1]=uz; l8[b8+2]=ux;
  l8[b8+3]=s3*ux*uy; l8[b8+4]=s3*uy*uz;
  l8[b8+5]=0.5f*(3.f*uz*uz-1.f);
  l8[b8+6]=s3*ux*uz; l8[b8+7]=0.5f*s3*(ux*ux-uy*uy);
  float ds = fmaxf(d, 1e-6f);
  const float cc = 0.632455532033676f; // sqrt(2/5)
  #pragma unroll
  for (int k=0;k<20;k++){
    float th = ((k+1)*PI_F)*ds/CUTOFF;
    rbf[(size_t)e*20+k] = cc*sinf(th)/ds;
  }
}

// tile-summed Wv: Wvs[8][128]
__global__ void xg_wvs(const float* __restrict__ Wv, float* __restrict__ Wvs){
  int h=threadIdx.x;
  #pragma unroll
  for (int c=0;c<3;c++){
    float s=0.f;
    for (int t=0;t<64;t++) s+=Wv[(size_t)(t*3+c)*128+h];
    Wvs[c*128+h]=s;
  }
  #pragma unroll
  for (int c=0;c<5;c++){
    float s=0.f;
    for (int t=0;t<32;t++) s+=Wv[(size_t)(192+t*5+c)*128+h];
    Wvs[(3+c)*128+h]=s;
  }
}

// ---------------------------------------------------------------- CSR build
__global__ __launch_bounds__(256) void xg_hist(const int* __restrict__ nei, int LE,
                                               int* deg_dst, int* deg_src){
  int i=blockIdx.x*256+threadIdx.x;
  if (i>=LE) return;
  atomicAdd(&deg_src[nei[i]],1);
  atomicAdd(&deg_dst[nei[LE+i]],1);
}

__global__ __launch_bounds__(1024) void xg_scan2(const int* __restrict__ degA, int* __restrict__ rpA,
                                                 const int* __restrict__ degB, int* __restrict__ rpB, int n){
  const int* deg = (blockIdx.x==0)? degA : degB;
  int* rp = (blockIdx.x==0)? rpA : rpB;
  __shared__ int wsum[16];
  int tid=threadIdx.x, lane=tid&63, wid=tid>>6;
  int carry=0;
  for (int base=0;base<n;base+=1024){
    int i=base+tid;
    int v=(i<n)?deg[i]:0;
    int x=v;
    #pragma unroll
    for (int off=1;off<64;off<<=1){int y=__shfl_up(x,off); if(lane>=off)x+=y;}
    if (lane==63) wsum[wid]=x;
    __syncthreads();
    if (wid==0 && lane<16){
      int s=wsum[lane];
      #pragma unroll
      for (int off=1;off<16;off<<=1){int y=__shfl_up(s,off); if(lane>=off)s+=y;}
      wsum[lane]=s;
    }
    __syncthreads();
    int woff=(wid==0)?0:wsum[wid-1];
    if (i<n) rp[i]=carry+woff+x-v;
    carry+=wsum[15];
    __syncthreads();
  }
  if (tid==0) rp[n]=carry;
}

__global__ __launch_bounds__(256) void xg_fill(const int* __restrict__ nei, int LE,
    const int* __restrict__ rp_dst, int* cur_dst, int* col_dst,
    const int* __restrict__ rp_src, int* cur_src, int* col_src){
  int i=blockIdx.x*256+threadIdx.x;
  if (i>=LE) return;
  int s=nei[i], d=nei[LE+i];
  int pd = rp_dst[d] + atomicAdd(&cur_dst[d],1);
  col_dst[pd] = s;  // store le_src for fwd gather
  int ps = rp_src[s] + atomicAdd(&cur_src[s],1);
  col_src[ps] = d;  // store le_dst for bwd gather
}

// ---------------------------------------------------------------- gathers
// 8 rows per wave (8 independent load streams), float2 lanes, branchless
// predication, next-iter col[] indices prefetched ahead of FMA consume.
__global__ __launch_bounds__(256) void xg_gather1(const float* __restrict__ g,
  const int* __restrict__ rp, const int* __restrict__ col,
  float* __restrict__ out, int E)
{
  const float2* g2 = (const float2*)g;
  float2* out2 = (float2*)out;
  int w=(blockIdx.x*256+threadIdx.x)>>6, lane=threadIdx.x&63;
  int r0 = w*8;
  if (r0>=E) return;
  int s[8], e[8];
  #pragma unroll
  for (int j=0;j<8;j++){
    int r=r0+j;
    s[j]=(r<E)?rp[r]:0; e[j]=(r<E)?rp[r+1]:0;
  }
  float2 acc[8];
  #pragma unroll
  for (int j=0;j<8;j++) acc[j]=make_float2(0.f,0.f);

  int c[8]; float m[8];
  int live=0;
  #pragma unroll
  for (int j=0;j<8;j++){
    bool a = s[j]<e[j]; live |= (int)a;
    c[j]=a?col[s[j]]:0; m[j]=a?1.f:0.f;
  }
  while (live){
    float2 v[8];
    #pragma unroll
    for (int j=0;j<8;j++) v[j]=g2[(size_t)c[j]*64+lane];
    // prefetch next-iter indices while v loads are in flight
    int cn[8]; float mn[8];
    live=0;
    #pragma unroll
    for (int j=0;j<8;j++){
      s[j]++;
      bool a = s[j]<e[j]; live |= (int)a;
      cn[j]=a?col[s[j]]:0; mn[j]=a?1.f:0.f;
    }
    #pragma unroll
    for (int j=0;j<8;j++){
      acc[j].x=fmaf(v[j].x,m[j],acc[j].x); acc[j].y=fmaf(v[j].y,m[j],acc[j].y);
      c[j]=cn[j]; m[j]=mn[j];
    }
  }
  #pragma unroll
  for (int j=0;j<8;j++){
    int r=r0+j;
    if (r<E) out2[(size_t)r*64+lane]=acc[j];
  }
}

// bwd fused: G = gather(g_agg by src-CSR, 8 rows/wave); gate/gpre recomputed;
// g_x += gate*G; g_rbf[e][k] += sum_h (x_l*G*silu'(gpre))[h]*Wr[k][h] via DPP.
__global__ __launch_bounds__(256) void xg_convgather(const float* __restrict__ g,
  const int* __restrict__ rp, const int* __restrict__ col,
  const float* __restrict__ xl, float* __restrict__ g_x,
  const float* __restrict__ rbf, float* __restrict__ g_rbf,
  const float* __restrict__ Wr_l, int E)
{
  __shared__ float wr[2560];
  for (int i=threadIdx.x;i<2560;i+=256) wr[i]=Wr_l[i];
  __syncthreads();
  const float2* g2 = (const float2*)g;
  const float2* xl2 = (const float2*)xl;
  float2* gx2 = (float2*)g_x;
  const float2* wr2 = (const float2*)wr;
  int w=(blockIdx.x*256+threadIdx.x)>>6, lane=threadIdx.x&63;
  int r0 = w*8;
  if (r0>=E) return;
  int s[8], e[8];
  #pragma unroll
  for (int j=0;j<8;j++){
    int r=r0+j;
    s[j]=(r<E)?rp[r]:0; e[j]=(r<E)?rp[r+1]:0;
  }
  float2 acc[8];
  #pragma unroll
  for (int j=0;j<8;j++) acc[j]=make_float2(0.f,0.f);

  int c[8]; float m[8];
  int live=0;
  #pragma unroll
  for (int j=0;j<8;j++){
    bool a = s[j]<e[j]; live |= (int)a;
    c[j]=a?col[s[j]]:0; m[j]=a?1.f:0.f;
  }
  while (live){
    float2 v[8];
    #pragma unroll
    for (int j=0;j<8;j++) v[j]=g2[(size_t)c[j]*64+lane];
    int cn[8]; float mn[8];
    live=0;
    #pragma unroll
    for (int j=0;j<8;j++){
      s[j]++;
      bool a = s[j]<e[j]; live |= (int)a;
      cn[j]=a?col[s[j]]:0; mn[j]=a?1.f:0.f;
    }
    #pragma unroll
    for (int j=0;j<8;j++){
      acc[j].x=fmaf(v[j].x,m[j],acc[j].x); acc[j].y=fmaf(v[j].y,m[j],acc[j].y);
      c[j]=cn[j]; m[j]=mn[j];
    }
  }

  #pragma unroll
  for (int j=0;j<8;j++){
    int row=r0+j;
    if (row>=E) break;
    float rk[20];
    #pragma unroll
    for (int k=0;k<20;k++) rk[k]=rbf[(size_t)row*20+k];
    float gp0=0.f,gp1=0.f;
    #pragma unroll
    for (int k=0;k<20;k++){
      float2 w2=wr2[k*64+lane];
      gp0=fmaf(rk[k],w2.x,gp0); gp1=fmaf(rk[k],w2.y,gp1);
    }
    float ss0=1.f/(1.f+__expf(-gp0)), ss1=1.f/(1.f+__expf(-gp1));
    float gate0=gp0*ss0, gate1=gp1*ss1;
    float sd0=ss0*(1.f+gp0*(1.f-ss0)), sd1=ss1*(1.f+gp1*(1.f-ss1));
    float2 a = acc[j];
    size_t b=(size_t)row*64+lane;
    float2 x2v = xl2[b];
    float gg0 = x2v.x*a.x*sd0, gg1 = x2v.y*a.y*sd1;
    float2 gx = gx2[b];
    gx.x += gate0*a.x; gx.y += gate1*a.y;
    gx2[b] = gx;
    #pragma unroll
    for (int k=0;k<20;k++){
      float2 w2=wr2[k*64+lane];
      float v = wave_sum63(fmaf(gg0, w2.x, gg1*w2.y));
      if (lane==63) g_rbf[(size_t)row*20+k] += v;
    }
  }
}

// ---------------------------------------------------------------- outputs
__global__ __launch_bounds__(256) void xg_out(const float* __restrict__ x3,
  const float* __restrict__ env_a, const float* __restrict__ w_out,
  const int* __restrict__ eidx, const int* __restrict__ abatch,
  float* __restrict__ g_env, float* __restrict__ results, int E)
{
  __shared__ float bins[64];
  __shared__ float wsh[128];
  int tid=threadIdx.x;
  if (tid<64) bins[tid]=0.f;
  if (tid<128) wsh[tid]=w_out[tid];
  __syncthreads();
  int lane=tid&63;
  int gw = blockIdx.x*4 + (tid>>6);
  int stride = gridDim.x*4;
  for (int e=gw; e<E; e+=stride){
    size_t b=(size_t)e*128;
    float v = wave_sum63(x3[b+lane]*wsh[lane] + x3[b+lane+64]*wsh[lane+64]);
    if (lane==63){
      g_env[e]=v;
      float ee=v*env_a[e];
      if (ee!=0.f) atomicAdd(&bins[abatch[eidx[e]]], ee);
    }
  }
  __syncthreads();
  if (tid<64){ float bb=bins[tid]; if (bb!=0.f) atomicAdd(&results[tid], bb); }
}

__global__ __launch_bounds__(256) void xg_gxinit(const float* __restrict__ env_a,
  const float* __restrict__ w_out, float* __restrict__ g_x, int E){
  size_t i = (size_t)blockIdx.x*256+threadIdx.x;
  if (i >= (size_t)E*128) return;
  int e = (int)(i>>7), h = (int)(i&127);
  g_x[i] = env_a[e]*w_out[h];
}

// rsh path bwd: g_l8[c] = sum_h g_x0[h]*silu'(vpre[h])*Wvs[c][h]
__global__ __launch_bounds__(256) void xg_vpath(const float* __restrict__ g_x,
  const float* __restrict__ l8, const float* __restrict__ Wvs,
  float* __restrict__ g_l8, int E)
{
  __shared__ float W[1024];
  for (int i=threadIdx.x;i<1024;i+=256) W[i]=Wvs[i];
  __syncthreads();
  int gw=(blockIdx.x*256+threadIdx.x)>>6, lane=threadIdx.x&63;
  if (gw>=E) return;
  float l[8];
  #pragma unroll
  for (int c=0;c<8;c++) l[c]=l8[(size_t)gw*8+c];
  float vp0=0.f, vp1=0.f;
  #pragma unroll
  for (int c=0;c<8;c++){ vp0=fmaf(l[c],W[c*128+lane],vp0); vp1=fmaf(l[c],W[c*128+lane+64],vp1); }
  size_t b=(size_t)gw*128;
  float gv0 = g_x[b+lane]*silud(vp0);
  float gv1 = g_x[b+lane+64]*silud(vp1);
  #pragma unroll
  for (int c=0;c<8;c++){
    float v = wave_sum63(fmaf(gv0, W[c*128+lane], gv1*W[c*128+lane+64]));
    if (lane==63) g_l8[(size_t)gw*8+c] = v;
  }
}

// eattr path: g_env += vec.eattr; edge_grads[k] = env * vec . eagrad[:,k,:]
__global__ __launch_bounds__(256) void xg_eattrbwd(const float* __restrict__ vecb,
  const float* __restrict__ eattr, const float* __restrict__ eagr,
  const float* __restrict__ env_a, float* __restrict__ g_env,
  float* __restrict__ eg, int E)
{
  int gw=(blockIdx.x*256+threadIdx.x)>>6, lane=threadIdx.x&63;
  if (gw>=E) return;
  const float* vr = vecb + (size_t)gw*172;
  const float* ar = eattr + (size_t)gw*169;
  const float* gr = eagr + (size_t)gw*507;
  float se=0.f,e0=0.f,e1=0.f,e2=0.f;
  for (int f=lane; f<169; f+=64){
    float v=vr[f];
    se=fmaf(v,ar[f],se);
    e0=fmaf(v,gr[f],e0);
    e1=fmaf(v,gr[169+f],e1);
    e2=fmaf(v,gr[338+f],e2);
  }
  se=wave_sum63(se); e0=wave_sum63(e0); e1=wave_sum63(e1); e2=wave_sum63(e2);
  if (lane==63){
    g_env[gw] += se;
    float en = env_a[gw];
    eg[(size_t)gw*3+0]=e0*en; eg[(size_t)gw*3+1]=e1*en; eg[(size_t)gw*3+2]=e2*en;
  }
}

// final: g_d (env + rbf paths), g_u -> g_bv, + edge_grads, scatter to force
__global__ __launch_bounds__(256) void xg_force(const float* __restrict__ bv,
  const float* __restrict__ d_a, const float* __restrict__ g_env,
  const float* __restrict__ g_rbf, const float* __restrict__ g_l8,
  const float* __restrict__ eg, const int* __restrict__ eidx,
  float* __restrict__ force, int E)
{
  int e = blockIdx.x*256+threadIdx.x;
  if (e>=E) return;
  float d = d_a[e];
  float inv = 1.f/d;
  float xx = d/CUTOFF;
  float x2=xx*xx, x4=x2*x2, x5=x4*xx, x6=x5*xx;
  float g_d = g_env[e] * ((d<CUTOFF)? ((-105.f*x4+210.f*x5-105.f*x6)/CUTOFF) : 0.f);
  const float cc=0.632455532033676f;
  float tie = (d>1e-6f)?1.f:0.5f;
  float acc=0.f;
  #pragma unroll
  for (int k=0;k<20;k++){
    float a=(k+1)*PI_F;
    float th=a*d/CUTOFF;
    float sn=sinf(th), cs=cosf(th);
    float drb = cc*((a/CUTOFF)*cs*d - sn)*inv*inv;
    acc = fmaf(g_rbf[(size_t)e*20+k], drb, acc);
  }
  g_d += acc*tie;
  size_t b3=(size_t)e*3, b8=(size_t)e*8;
  float ux=bv[b3+0]*inv, uy=bv[b3+1]*inv, uz=bv[b3+2]*inv;
  const float s3=1.7320508075688772f;
  float G1y=g_l8[b8+0], G1z=g_l8[b8+1], G1x=g_l8[b8+2];
  float A=g_l8[b8+3], B=g_l8[b8+4], Cq=g_l8[b8+5], D=g_l8[b8+6], F=g_l8[b8+7];
  float gux = G1x + s3*(uy*A + uz*D + ux*F);
  float guy = G1y + s3*(ux*A + uz*B) - s3*uy*F;
  float guz = G1z + s3*uy*B + 3.f*uz*Cq + s3*ux*D;
  float ud = ux*gux+uy*guy+uz*guz;
  float gbx = (gux-ux*ud)*inv + g_d*ux;
  float gby = (guy-uy*ud)*inv + g_d*uy;
  float gbz = (guz-uz*ud)*inv + g_d*uz;
  float fx = gbx + eg[b3+0];
  float fy = gby + eg[b3+1];
  float fz = gbz + eg[b3+2];
  int s=eidx[e], t=eidx[E+e];
  atomicAdd(&force[s*3+0],-fx); atomicAdd(&force[s*3+1],-fy); atomicAdd(&force[s*3+2],-fz);
  atomicAdd(&force[t*3+0], fx); atomicAdd(&force[t*3+1], fy); atomicAdd(&force[t*3+2], fz);
}

// ================================================================ launch
extern "C" void kernel_launch(void* const* d_in, const int* in_sizes, int n_in,
                              void* d_out, int out_size, void* d_ws, size_t ws_size,
                              hipStream_t stream)
{
  const float* pos   = (const float*)d_in[0];
  const float* eattr = (const float*)d_in[1];
  const float* eagr  = (const float*)d_in[2];
  const float* W_mat = (const float*)d_in[3];
  const float* b_mat = (const float*)d_in[4];
  const float* W_emb = (const float*)d_in[5];
  const float* b_emb = (const float*)d_in[6];
  const float* Wv    = (const float*)d_in[7];
  const float* Wr    = (const float*)d_in[8];
  const float* Wx    = (const float*)d_in[9];
  const float* w_out = (const float*)d_in[10];
  const int* eidx    = (const int*)d_in[11];
  const int* nei     = (const int*)d_in[12];
  const int* abatch  = (const int*)d_in[13];

  const int E  = in_sizes[1]/169;
  const int LE = in_sizes[12]/2;

  float* p = (float*)d_ws;
  auto alloc=[&](size_t n){ float* q=p; p+=n; return q; };
  float* bv    = alloc((size_t)3*E);
  float* d_a   = alloc(E);
  float* env_a = alloc(E);
  float* l8    = alloc((size_t)8*E);
  float* rbf   = alloc((size_t)20*E);
  float* g_env = alloc(E);
  float* g_l8  = alloc((size_t)8*E);
  float* eg    = alloc((size_t)3*E);
  float* Wvs   = alloc(1024);
  float* h_pre = alloc((size_t)128*E);
  float* x0    = alloc((size_t)128*E);
  float* x1    = alloc((size_t)128*E);
  float* x2    = alloc((size_t)128*E);
  float* apre0 = alloc((size_t)128*E);
  float* apre1 = alloc((size_t)128*E);
  float* apre2 = alloc((size_t)128*E);
  float* bufA  = alloc((size_t)128*E);   // m / x3 / g_agg target
  float* bufB  = alloc((size_t)128*E);   // agg / g_agg / g_hpre
  float* g_x   = alloc((size_t)128*E);
  float* g_rbf = alloc((size_t)20*E);    // zero-region start
  int* ip = (int*)p;
  int* deg_dst = ip; ip+=E;
  int* deg_src = ip; ip+=E;
  int* cur_dst = ip; ip+=E;
  int* cur_src = ip; ip+=E;              // zero-region end (24E * 4B)
  int* rp_dst  = ip; ip+=E+1;
  int* rp_src  = ip; ip+=E+1;
  int* col_dst = ip; ip+=LE;
  int* col_src = ip; ip+=LE;
  float* vecb  = apre0;                  // (E x 169, ld 172) aliases apre0/1

  float* results = (float*)d_out;
  float* force   = results + 64;

  hipMemsetAsync(d_out, 0, (size_t)out_size*sizeof(float), stream);
  hipMemsetAsync(g_rbf, 0, (size_t)24*E*sizeof(float), stream);

  float* xsm[4]   = {x0,x1,x2,bufA};
  float* apres[3] = {apre0,apre1,apre2};

  const int gE  = (E+255)/256;
  const int gLE = (LE+255)/256;
  const int gW  = (E+3)/4;          // one wave per edge (1-row kernels)
  const int gW8 = (E+31)/32;        // 4 waves x 8 rows per block
  dim3 gg((E+63)/64, 1);

  // forward
  xg_geom<<<gE,256,0,stream>>>(pos, eidx, E, bv, d_a, env_a, l8, rbf);
  xg_wvs<<<1,128,0,stream>>>(Wv, Wvs);
  xg_hist<<<gLE,256,0,stream>>>(nei, LE, deg_dst, deg_src);
  xg_scan2<<<2,1024,0,stream>>>(deg_dst, rp_dst, deg_src, rp_src, E);
  xg_fill<<<gLE,256,0,stream>>>(nei, LE, rp_dst, cur_dst, col_dst, rp_src, cur_src, col_src);

  xg_gemm<PRE_SCALE_ROW,POST_BIAS,false><<<gg,256,0,stream>>>(
      eattr,169,169, W_mat,128,128, h_pre,128, env_a,nullptr,nullptr, b_mat,
      nullptr,nullptr,nullptr, E);
  xg_gemm<PRE_SILU,POST_X0,false><<<gg,256,0,stream>>>(
      h_pre,128,128, W_emb,128,128, x0,128, nullptr,nullptr,nullptr, b_emb,
      l8,Wvs,nullptr, E);

  for (int l=0;l<3;l++) {
    // m = silu(rbf@Wr_l) * x_l  (fused gate+mul)
    xg_gemm<PRE_NONE,POST_GATE,false><<<gg,256,0,stream>>>(
        rbf,20,20, Wr+(size_t)l*2560,128,128, bufA,128,
        nullptr,nullptr, xsm[l], nullptr,nullptr,nullptr,nullptr, E);
    xg_gather1<<<gW8,256,0,stream>>>(bufA, rp_dst, col_dst, bufB, E);
    xg_gemm<PRE_NONE,POST_CONV,false><<<gg,256,0,stream>>>(
        bufB,128,128, Wx+(size_t)l*16384,128,128, apres[l],128,
        nullptr,nullptr, xsm[l], nullptr,nullptr,nullptr, xsm[l+1], E);
  }

  xg_out<<<512,256,0,stream>>>(bufA, env_a, w_out, eidx, abatch, g_env, results, E);

  // backward
  xg_gxinit<<<(int)(((size_t)E*128+255)/256),256,0,stream>>>(env_a, w_out, g_x, E);
  for (int l=2;l>=0;l--) {
    xg_gemm<PRE_MUL_SILUD,POST_PLAIN,true><<<gg,256,0,stream>>>(
        g_x,128,128, Wx+(size_t)l*16384,128,128, bufB,128,
        nullptr, apres[l], nullptr, nullptr,nullptr,nullptr,nullptr, E);
    xg_convgather<<<gW8,256,0,stream>>>(bufB, rp_src, col_src, xsm[l], g_x,
                                        rbf, g_rbf, Wr+(size_t)l*2560, E);
  }
  xg_vpath<<<gW,256,0,stream>>>(g_x, l8, Wvs, g_l8, E);
  xg_gemm<PRE_NONE,POST_MUL_SILUD,true><<<gg,256,0,stream>>>(
      g_x,128,128, W_emb,128,128, bufB,128, nullptr,nullptr, h_pre,
      nullptr,nullptr,nullptr,nullptr, E);
  dim3 g8((E+63)/64, 2);
  xg_gemm<PRE_NONE,POST_PLAIN,true><<<g8,256,0,stream>>>(
      bufB,128,128, W_mat,128,169, vecb,172,
      nullptr,nullptr,nullptr,nullptr,nullptr,nullptr,nullptr, E);
  xg_eattrbwd<<<gW,256,0,stream>>>(vecb, eattr, eagr, env_a, g_env, eg, E);
  xg_force<<<gE,256,0,stream>>>(bv, d_a, g_env, g_rbf, g_l8, eg, eidx, force, E);
}

// Round 4
// 3422.361 us; speedup vs baseline: 1.0363x; 1.0363x over previous
//
#include <hip/hip_runtime.h>
#include <cstdint>

// Round 7: convgather rebalanced after R3 regression (occupancy 82->43 cancelled
// the 8-stream ILP: 6.6x4 ~= 3.4x8 outstanding loads).
// - xg_convgather: 4 rows/wave (short epilogue, full occupancy) x 2-edge unroll
//   per row -> 8 loads in flight/wave, ~64 outstanding/SIMD (2.4x R2's 26).
// - xg_gather1: kept at 8-row + index prefetch (improved ~-60us/dispatch by
//   subtraction in R3: total +95 while convgather +288).
// GEMM unchanged.

#define CUTOFF 5.0f
#define PI_F 3.14159265358979323846f

__device__ __forceinline__ float siluf(float v){ float s=1.f/(1.f+__expf(-v)); return v*s; }
__device__ __forceinline__ float silud(float v){ float s=1.f/(1.f+__expf(-v)); return s*(1.f+v*(1.f-s)); }

// ---- DPP wave64 sum: result valid in lane 63 (VALU pipe, no LDS traffic)
template<int CTRL>
__device__ __forceinline__ float dpp_radd(float x){
  int y = __builtin_amdgcn_update_dpp(0, __float_as_int(x), CTRL, 0xf, 0xf, false);
  return x + __int_as_float(y);
}
__device__ __forceinline__ float wave_sum63(float x){
  x = dpp_radd<0x111>(x);  // row_shr:1
  x = dpp_radd<0x112>(x);  // row_shr:2
  x = dpp_radd<0x114>(x);  // row_shr:4
  x = dpp_radd<0x118>(x);  // row_shr:8
  x = dpp_radd<0x142>(x);  // row_bcast:15
  x = dpp_radd<0x143>(x);  // row_bcast:31 -> lane63 has full sum
  return x;
}

constexpr int PRE_NONE=0, PRE_SCALE_ROW=1, PRE_SILU=2, PRE_MUL_SILUD=3;
constexpr int POST_PLAIN=0, POST_BIAS=1, POST_GATE=2, POST_X0=3, POST_CONV=4, POST_MUL_SILUD=5;

// ---------------------------------------------------------------- GEMM
template<int PRE, int POST, bool BT>
__global__ __launch_bounds__(256) void xg_gemm(
    const float* __restrict__ A, int ldA, int K,
    const float* __restrict__ B, int ldB, int N,
    float* __restrict__ C, int ldC,
    const float* __restrict__ rowscale,   // PRE_SCALE_ROW
    const float* __restrict__ auxA,       // PRE_MUL_SILUD  (ld 128)
    const float* __restrict__ auxC,       // POST_CONV / POST_GATE (x_l) / POST_MUL_SILUD (h_pre)
    const float* __restrict__ bias,       // POST_BIAS / POST_X0
    const float* __restrict__ l8g,        // POST_X0 (E x 8 row-major)
    const float* __restrict__ Wvsg,       // POST_X0 (8 x 128)
    float* __restrict__ C2,               // POST_CONV x_{l+1}
    int E)
{
  __shared__ float Alds[64][36];          // 36-float row stride: 144B, 16B aligned
  __shared__ float Blds[32][132];
  __shared__ float l8s[8][64];
  __shared__ float WvsS[8][128];

  const int tid = threadIdx.x;
  const int e0 = blockIdx.x*64;
  const int n0 = blockIdx.y*128;

  if constexpr (POST==POST_X0) {
    for (int i=tid;i<1024;i+=256) WvsS[i>>7][i&127] = Wvsg[i];
    for (int i=tid;i<512;i+=256) {
      int r=i>>3, c=i&7; int e=e0+r;
      l8s[c][r] = (e<E)? l8g[(size_t)e*8+c] : 0.f;
    }
  }

  const int ty = tid>>5, tx = tid&31;
  float acc[8][4];
  #pragma unroll
  for (int i=0;i<8;i++){acc[i][0]=0.f;acc[i][1]=0.f;acc[i][2]=0.f;acc[i][3]=0.f;}

  for (int k0=0;k0<K;k0+=32) {
    __syncthreads();
    { // A tile 64x32
      const int kk = tid&31, rb = tid>>5;
      #pragma unroll
      for (int p=0;p<8;p++) {
        int r = rb + p*8;
        int e = e0+r, k = k0+kk;
        float v = 0.f;
        if (e<E && k<K) {
          v = A[(size_t)e*ldA + k];
          if constexpr (PRE==PRE_SCALE_ROW) v *= rowscale[e];
          if constexpr (PRE==PRE_SILU)      v = siluf(v);
          if constexpr (PRE==PRE_MUL_SILUD) v *= silud(auxA[(size_t)e*128+k]);
        }
        Alds[r][kk] = v;
      }
    }
    if constexpr (!BT) { // B row-major KxN
      const int n = tid&127, kb = tid>>7;
      #pragma unroll
      for (int p=0;p<16;p++) {
        int kk = kb + p*2;
        int k = k0+kk, nn = n0+n;
        Blds[kk][n] = (k<K && nn<N) ? B[(size_t)k*ldB+nn] : 0.f;
      }
    } else {             // B = W^T, W row-major NxK (ldB)
      const int kk = tid&31, nb = tid>>5;
      #pragma unroll
      for (int p=0;p<16;p++) {
        int n = nb + p*8;
        int k = k0+kk, nn = n0+n;
        Blds[kk][n] = (k<K && nn<N) ? B[(size_t)nn*ldB+k] : 0.f;
      }
    }
    __syncthreads();
    #pragma unroll
    for (int kk4=0;kk4<8;kk4++) {
      float4 b0 = *(const float4*)&Blds[kk4*4+0][tx*4];
      float4 b1 = *(const float4*)&Blds[kk4*4+1][tx*4];
      float4 b2 = *(const float4*)&Blds[kk4*4+2][tx*4];
      float4 b3 = *(const float4*)&Blds[kk4*4+3][tx*4];
      #pragma unroll
      for (int i=0;i<8;i++) {
        float4 a = *(const float4*)&Alds[ty*8+i][kk4*4];
        acc[i][0] = fmaf(a.x,b0.x,acc[i][0]);
        acc[i][1] = fmaf(a.x,b0.y,acc[i][1]);
        acc[i][2] = fmaf(a.x,b0.z,acc[i][2]);
        acc[i][3] = fmaf(a.x,b0.w,acc[i][3]);
        acc[i][0] = fmaf(a.y,b1.x,acc[i][0]);
        acc[i][1] = fmaf(a.y,b1.y,acc[i][1]);
        acc[i][2] = fmaf(a.y,b1.z,acc[i][2]);
        acc[i][3] = fmaf(a.y,b1.w,acc[i][3]);
        acc[i][0] = fmaf(a.z,b2.x,acc[i][0]);
        acc[i][1] = fmaf(a.z,b2.y,acc[i][1]);
        acc[i][2] = fmaf(a.z,b2.z,acc[i][2]);
        acc[i][3] = fmaf(a.z,b2.w,acc[i][3]);
        acc[i][0] = fmaf(a.w,b3.x,acc[i][0]);
        acc[i][1] = fmaf(a.w,b3.y,acc[i][1]);
        acc[i][2] = fmaf(a.w,b3.z,acc[i][2]);
        acc[i][3] = fmaf(a.w,b3.w,acc[i][3]);
      }
    }
  }

  const int cbase = n0 + tx*4;
  #pragma unroll
  for (int i=0;i<8;i++) {
    int e = e0 + ty*8 + i;
    if (e>=E) break;
    size_t ci = (size_t)e*ldC + cbase;
    float4 v = make_float4(acc[i][0],acc[i][1],acc[i][2],acc[i][3]);
    if constexpr (POST==POST_BIAS) {
      v.x+=bias[cbase]; v.y+=bias[cbase+1]; v.z+=bias[cbase+2]; v.w+=bias[cbase+3];
      *(float4*)&C[ci]=v;
    } else if constexpr (POST==POST_GATE) { // m = silu(acc) * x_l
      float4 xl4 = *(const float4*)&auxC[(size_t)e*128 + cbase];
      v.x=siluf(v.x)*xl4.x; v.y=siluf(v.y)*xl4.y;
      v.z=siluf(v.z)*xl4.z; v.w=siluf(v.w)*xl4.w;
      *(float4*)&C[ci]=v;
    } else if constexpr (POST==POST_X0) {
      float vp0=0.f,vp1=0.f,vp2=0.f,vp3=0.f;
      int r = ty*8+i;
      #pragma unroll
      for (int c=0;c<8;c++){
        float lc = l8s[c][r];
        vp0=fmaf(lc,WvsS[c][cbase+0],vp0); vp1=fmaf(lc,WvsS[c][cbase+1],vp1);
        vp2=fmaf(lc,WvsS[c][cbase+2],vp2); vp3=fmaf(lc,WvsS[c][cbase+3],vp3);
      }
      v.x += bias[cbase+0] + siluf(vp0);
      v.y += bias[cbase+1] + siluf(vp1);
      v.z += bias[cbase+2] + siluf(vp2);
      v.w += bias[cbase+3] + siluf(vp3);
      *(float4*)&C[ci]=v;
    } else if constexpr (POST==POST_CONV) {
      *(float4*)&C[ci]=v; // apre_l
      float4 xl = *(const float4*)&auxC[(size_t)e*128 + cbase];
      float4 o = make_float4(xl.x+siluf(v.x), xl.y+siluf(v.y),
                             xl.z+siluf(v.z), xl.w+siluf(v.w));
      *(float4*)&C2[ci]=o; // x_{l+1}
    } else if constexpr (POST==POST_MUL_SILUD) {
      float4 a4 = *(const float4*)&auxC[(size_t)e*128 + cbase];
      v.x*=silud(a4.x); v.y*=silud(a4.y); v.z*=silud(a4.z); v.w*=silud(a4.w);
      *(float4*)&C[ci]=v;
    } else { // POST_PLAIN
      if (cbase+3 < N) { *(float4*)&C[ci]=v; }
      else {
        float vv[4]={v.x,v.y,v.z,v.w};
        #pragma unroll
        for (int j=0;j<4;j++) if (cbase+j<N) C[ci+j]=vv[j];
      }
    }
  }
}

// ---------------------------------------------------------------- geometry
__global__ __launch_bounds__(256) void xg_geom(const float* __restrict__ pos,
  const int* __restrict__ eidx, int E,
  float* __restrict__ bv, float* __restrict__ d_a, float* __restrict__ env_a,
  float* __restrict__ l8, float* __restrict__ rbf)
{
  int e = blockIdx.x*256+threadIdx.x;
  if (e>=E) return;
  int s = eidx[e], t = eidx[E+e];
  float bx = pos[s*3+0]-pos[t*3+0];
  float by = pos[s*3+1]-pos[t*3+1];
  float bz = pos[s*3+2]-pos[t*3+2];
  float d = sqrtf(bx*bx+by*by+bz*bz + 1e-12f);
  bv[(size_t)e*3+0]=bx; bv[(size_t)e*3+1]=by; bv[(size_t)e*3+2]=bz;
  d_a[e]=d;
  float xx = d/CUTOFF;
  float x2=xx*xx, x4=x2*x2, x5=x4*xx, x6=x5*xx, x7=x6*xx;
  env_a[e] = (d<CUTOFF)? (1.f-21.f*x5+35.f*x6-15.f*x7) : 0.f;
  float inv = 1.f/d;
  float ux=bx*inv, uy=by*inv, uz=bz*inv;
  const float s3 = 1.7320508075688772f;
  size_t b8=(size_t)e*8;
  l8[b8+0]=uy; l8[b8+1]=uz; l8[b8+2]=ux;
  l8[b8+3]=s3*ux*uy; l8[b8+4]=s3*uy*uz;
  l8[b8+5]=0.5f*(3.f*uz*uz-1.f);
  l8[b8+6]=s3*ux*uz; l8[b8+7]=0.5f*s3*(ux*ux-uy*uy);
  float ds = fmaxf(d, 1e-6f);
  const float cc = 0.632455532033676f; // sqrt(2/5)
  #pragma unroll
  for (int k=0;k<20;k++){
    float th = ((k+1)*PI_F)*ds/CUTOFF;
    rbf[(size_t)e*20+k] = cc*sinf(th)/ds;
  }
}

// tile-summed Wv: Wvs[8][128]
__global__ void xg_wvs(const float* __restrict__ Wv, float* __restrict__ Wvs){
  int h=threadIdx.x;
  #pragma unroll
  for (int c=0;c<3;c++){
    float s=0.f;
    for (int t=0;t<64;t++) s+=Wv[(size_t)(t*3+c)*128+h];
    Wvs[c*128+h]=s;
  }
  #pragma unroll
  for (int c=0;c<5;c++){
    float s=0.f;
    for (int t=0;t<32;t++) s+=Wv[(size_t)(192+t*5+c)*128+h];
    Wvs[(3+c)*128+h]=s;
  }
}

// ---------------------------------------------------------------- CSR build
__global__ __launch_bounds__(256) void xg_hist(const int* __restrict__ nei, int LE,
                                               int* deg_dst, int* deg_src){
  int i=blockIdx.x*256+threadIdx.x;
  if (i>=LE) return;
  atomicAdd(&deg_src[nei[i]],1);
  atomicAdd(&deg_dst[nei[LE+i]],1);
}

__global__ __launch_bounds__(1024) void xg_scan2(const int* __restrict__ degA, int* __restrict__ rpA,
                                                 const int* __restrict__ degB, int* __restrict__ rpB, int n){
  const int* deg = (blockIdx.x==0)? degA : degB;
  int* rp = (blockIdx.x==0)? rpA : rpB;
  __shared__ int wsum[16];
  int tid=threadIdx.x, lane=tid&63, wid=tid>>6;
  int carry=0;
  for (int base=0;base<n;base+=1024){
    int i=base+tid;
    int v=(i<n)?deg[i]:0;
    int x=v;
    #pragma unroll
    for (int off=1;off<64;off<<=1){int y=__shfl_up(x,off); if(lane>=off)x+=y;}
    if (lane==63) wsum[wid]=x;
    __syncthreads();
    if (wid==0 && lane<16){
      int s=wsum[lane];
      #pragma unroll
      for (int off=1;off<16;off<<=1){int y=__shfl_up(s,off); if(lane>=off)s+=y;}
      wsum[lane]=s;
    }
    __syncthreads();
    int woff=(wid==0)?0:wsum[wid-1];
    if (i<n) rp[i]=carry+woff+x-v;
    carry+=wsum[15];
    __syncthreads();
  }
  if (tid==0) rp[n]=carry;
}

__global__ __launch_bounds__(256) void xg_fill(const int* __restrict__ nei, int LE,
    const int* __restrict__ rp_dst, int* cur_dst, int* col_dst,
    const int* __restrict__ rp_src, int* cur_src, int* col_src){
  int i=blockIdx.x*256+threadIdx.x;
  if (i>=LE) return;
  int s=nei[i], d=nei[LE+i];
  int pd = rp_dst[d] + atomicAdd(&cur_dst[d],1);
  col_dst[pd] = s;  // store le_src for fwd gather
  int ps = rp_src[s] + atomicAdd(&cur_src[s],1);
  col_src[ps] = d;  // store le_dst for bwd gather
}

// ---------------------------------------------------------------- gathers
// gather1: 8 rows per wave, float2 lanes, branchless predication,
// next-iter col[] indices prefetched ahead of FMA consume.
__global__ __launch_bounds__(256) void xg_gather1(const float* __restrict__ g,
  const int* __restrict__ rp, const int* __restrict__ col,
  float* __restrict__ out, int E)
{
  const float2* g2 = (const float2*)g;
  float2* out2 = (float2*)out;
  int w=(blockIdx.x*256+threadIdx.x)>>6, lane=threadIdx.x&63;
  int r0 = w*8;
  if (r0>=E) return;
  int s[8], e[8];
  #pragma unroll
  for (int j=0;j<8;j++){
    int r=r0+j;
    s[j]=(r<E)?rp[r]:0; e[j]=(r<E)?rp[r+1]:0;
  }
  float2 acc[8];
  #pragma unroll
  for (int j=0;j<8;j++) acc[j]=make_float2(0.f,0.f);

  int c[8]; float m[8];
  int live=0;
  #pragma unroll
  for (int j=0;j<8;j++){
    bool a = s[j]<e[j]; live |= (int)a;
    c[j]=a?col[s[j]]:0; m[j]=a?1.f:0.f;
  }
  while (live){
    float2 v[8];
    #pragma unroll
    for (int j=0;j<8;j++) v[j]=g2[(size_t)c[j]*64+lane];
    // prefetch next-iter indices while v loads are in flight
    int cn[8]; float mn[8];
    live=0;
    #pragma unroll
    for (int j=0;j<8;j++){
      s[j]++;
      bool a = s[j]<e[j]; live |= (int)a;
      cn[j]=a?col[s[j]]:0; mn[j]=a?1.f:0.f;
    }
    #pragma unroll
    for (int j=0;j<8;j++){
      acc[j].x=fmaf(v[j].x,m[j],acc[j].x); acc[j].y=fmaf(v[j].y,m[j],acc[j].y);
      c[j]=cn[j]; m[j]=mn[j];
    }
  }
  #pragma unroll
  for (int j=0;j<8;j++){
    int r=r0+j;
    if (r<E) out2[(size_t)r*64+lane]=acc[j];
  }
}

// bwd fused: G = gather(g_agg by src-CSR); gate/gpre recomputed;
// g_x += gate*G; g_rbf[e][k] += sum_h (x_l*G*silu'(gpre))[h]*Wr[k][h] via DPP.
// 4 rows/wave (keeps occupancy + short epilogue) x 2-edge unroll (8 loads
// in flight) + index prefetch.
__global__ __launch_bounds__(256) void xg_convgather(const float* __restrict__ g,
  const int* __restrict__ rp, const int* __restrict__ col,
  const float* __restrict__ xl, float* __restrict__ g_x,
  const float* __restrict__ rbf, float* __restrict__ g_rbf,
  const float* __restrict__ Wr_l, int E)
{
  __shared__ float wr[2560];
  for (int i=threadIdx.x;i<2560;i+=256) wr[i]=Wr_l[i];
  __syncthreads();
  const float2* g2 = (const float2*)g;
  const float2* xl2 = (const float2*)xl;
  float2* gx2 = (float2*)g_x;
  const float2* wr2 = (const float2*)wr;
  int w=(blockIdx.x*256+threadIdx.x)>>6, lane=threadIdx.x&63;
  int r0 = w*4;
  if (r0>=E) return;
  int s[4], e[4];
  #pragma unroll
  for (int j=0;j<4;j++){
    int r=r0+j;
    s[j]=(r<E)?rp[r]:0; e[j]=(r<E)?rp[r+1]:0;
  }
  float2 acc[4];
  #pragma unroll
  for (int j=0;j<4;j++) acc[j]=make_float2(0.f,0.f);

  int c0[4], c1[4]; float m0[4], m1[4];
  int live=0;
  #pragma unroll
  for (int j=0;j<4;j++){
    bool a0 = s[j]  <e[j];
    bool a1 = s[j]+1<e[j];
    live |= (int)a0;
    c0[j]=a0?col[s[j]]:0;   m0[j]=a0?1.f:0.f;
    c1[j]=a1?col[s[j]+1]:0; m1[j]=a1?1.f:0.f;
  }
  while (live){
    float2 v0[4], v1[4];
    #pragma unroll
    for (int j=0;j<4;j++){
      v0[j]=g2[(size_t)c0[j]*64+lane];
      v1[j]=g2[(size_t)c1[j]*64+lane];
    }
    // prefetch next pair of indices while data loads are in flight
    int n0[4], n1[4]; float p0[4], p1[4];
    live=0;
    #pragma unroll
    for (int j=0;j<4;j++){
      s[j]+=2;
      bool a0 = s[j]  <e[j];
      bool a1 = s[j]+1<e[j];
      live |= (int)a0;
      n0[j]=a0?col[s[j]]:0;   p0[j]=a0?1.f:0.f;
      n1[j]=a1?col[s[j]+1]:0; p1[j]=a1?1.f:0.f;
    }
    #pragma unroll
    for (int j=0;j<4;j++){
      acc[j].x=fmaf(v0[j].x,m0[j],acc[j].x); acc[j].y=fmaf(v0[j].y,m0[j],acc[j].y);
      acc[j].x=fmaf(v1[j].x,m1[j],acc[j].x); acc[j].y=fmaf(v1[j].y,m1[j],acc[j].y);
      c0[j]=n0[j]; m0[j]=p0[j]; c1[j]=n1[j]; m1[j]=p1[j];
    }
  }

  #pragma unroll
  for (int j=0;j<4;j++){
    int row=r0+j;
    if (row>=E) break;
    float rk[20];
    #pragma unroll
    for (int k=0;k<20;k++) rk[k]=rbf[(size_t)row*20+k];
    float gp0=0.f,gp1=0.f;
    #pragma unroll
    for (int k=0;k<20;k++){
      float2 w2=wr2[k*64+lane];
      gp0=fmaf(rk[k],w2.x,gp0); gp1=fmaf(rk[k],w2.y,gp1);
    }
    float ss0=1.f/(1.f+__expf(-gp0)), ss1=1.f/(1.f+__expf(-gp1));
    float gate0=gp0*ss0, gate1=gp1*ss1;
    float sd0=ss0*(1.f+gp0*(1.f-ss0)), sd1=ss1*(1.f+gp1*(1.f-ss1));
    float2 a = acc[j];
    size_t b=(size_t)row*64+lane;
    float2 x2v = xl2[b];
    float gg0 = x2v.x*a.x*sd0, gg1 = x2v.y*a.y*sd1;
    float2 gx = gx2[b];
    gx.x += gate0*a.x; gx.y += gate1*a.y;
    gx2[b] = gx;
    #pragma unroll
    for (int k=0;k<20;k++){
      float2 w2=wr2[k*64+lane];
      float v = wave_sum63(fmaf(gg0, w2.x, gg1*w2.y));
      if (lane==63) g_rbf[(size_t)row*20+k] += v;
    }
  }
}

// ---------------------------------------------------------------- outputs
__global__ __launch_bounds__(256) void xg_out(const float* __restrict__ x3,
  const float* __restrict__ env_a, const float* __restrict__ w_out,
  const int* __restrict__ eidx, const int* __restrict__ abatch,
  float* __restrict__ g_env, float* __restrict__ results, int E)
{
  __shared__ float bins[64];
  __shared__ float wsh[128];
  int tid=threadIdx.x;
  if (tid<64) bins[tid]=0.f;
  if (tid<128) wsh[tid]=w_out[tid];
  __syncthreads();
  int lane=tid&63;
  int gw = blockIdx.x*4 + (tid>>6);
  int stride = gridDim.x*4;
  for (int e=gw; e<E; e+=stride){
    size_t b=(size_t)e*128;
    float v = wave_sum63(x3[b+lane]*wsh[lane] + x3[b+lane+64]*wsh[lane+64]);
    if (lane==63){
      g_env[e]=v;
      float ee=v*env_a[e];
      if (ee!=0.f) atomicAdd(&bins[abatch[eidx[e]]], ee);
    }
  }
  __syncthreads();
  if (tid<64){ float bb=bins[tid]; if (bb!=0.f) atomicAdd(&results[tid], bb); }
}

__global__ __launch_bounds__(256) void xg_gxinit(const float* __restrict__ env_a,
  const float* __restrict__ w_out, float* __restrict__ g_x, int E){
  size_t i = (size_t)blockIdx.x*256+threadIdx.x;
  if (i >= (size_t)E*128) return;
  int e = (int)(i>>7), h = (int)(i&127);
  g_x[i] = env_a[e]*w_out[h];
}

// rsh path bwd: g_l8[c] = sum_h g_x0[h]*silu'(vpre[h])*Wvs[c][h]
__global__ __launch_bounds__(256) void xg_vpath(const float* __restrict__ g_x,
  const float* __restrict__ l8, const float* __restrict__ Wvs,
  float* __restrict__ g_l8, int E)
{
  __shared__ float W[1024];
  for (int i=threadIdx.x;i<1024;i+=256) W[i]=Wvs[i];
  __syncthreads();
  int gw=(blockIdx.x*256+threadIdx.x)>>6, lane=threadIdx.x&63;
  if (gw>=E) return;
  float l[8];
  #pragma unroll
  for (int c=0;c<8;c++) l[c]=l8[(size_t)gw*8+c];
  float vp0=0.f, vp1=0.f;
  #pragma unroll
  for (int c=0;c<8;c++){ vp0=fmaf(l[c],W[c*128+lane],vp0); vp1=fmaf(l[c],W[c*128+lane+64],vp1); }
  size_t b=(size_t)gw*128;
  float gv0 = g_x[b+lane]*silud(vp0);
  float gv1 = g_x[b+lane+64]*silud(vp1);
  #pragma unroll
  for (int c=0;c<8;c++){
    float v = wave_sum63(fmaf(gv0, W[c*128+lane], gv1*W[c*128+lane+64]));
    if (lane==63) g_l8[(size_t)gw*8+c] = v;
  }
}

// eattr path: g_env += vec.eattr; edge_grads[k] = env * vec . eagrad[:,k,:]
__global__ __launch_bounds__(256) void xg_eattrbwd(const float* __restrict__ vecb,
  const float* __restrict__ eattr, const float* __restrict__ eagr,
  const float* __restrict__ env_a, float* __restrict__ g_env,
  float* __restrict__ eg, int E)
{
  int gw=(blockIdx.x*256+threadIdx.x)>>6, lane=threadIdx.x&63;
  if (gw>=E) return;
  const float* vr = vecb + (size_t)gw*172;
  const float* ar = eattr + (size_t)gw*169;
  const float* gr = eagr + (size_t)gw*507;
  float se=0.f,e0=0.f,e1=0.f,e2=0.f;
  for (int f=lane; f<169; f+=64){
    float v=vr[f];
    se=fmaf(v,ar[f],se);
    e0=fmaf(v,gr[f],e0);
    e1=fmaf(v,gr[169+f],e1);
    e2=fmaf(v,gr[338+f],e2);
  }
  se=wave_sum63(se); e0=wave_sum63(e0); e1=wave_sum63(e1); e2=wave_sum63(e2);
  if (lane==63){
    g_env[gw] += se;
    float en = env_a[gw];
    eg[(size_t)gw*3+0]=e0*en; eg[(size_t)gw*3+1]=e1*en; eg[(size_t)gw*3+2]=e2*en;
  }
}

// final: g_d (env + rbf paths), g_u -> g_bv, + edge_grads, scatter to force
__global__ __launch_bounds__(256) void xg_force(const float* __restrict__ bv,
  const float* __restrict__ d_a, const float* __restrict__ g_env,
  const float* __restrict__ g_rbf, const float* __restrict__ g_l8,
  const float* __restrict__ eg, const int* __restrict__ eidx,
  float* __restrict__ force, int E)
{
  int e = blockIdx.x*256+threadIdx.x;
  if (e>=E) return;
  float d = d_a[e];
  float inv = 1.f/d;
  float xx = d/CUTOFF;
  float x2=xx*xx, x4=x2*x2, x5=x4*xx, x6=x5*xx;
  float g_d = g_env[e] * ((d<CUTOFF)? ((-105.f*x4+210.f*x5-105.f*x6)/CUTOFF) : 0.f);
  const float cc=0.632455532033676f;
  float tie = (d>1e-6f)?1.f:0.5f;
  float acc=0.f;
  #pragma unroll
  for (int k=0;k<20;k++){
    float a=(k+1)*PI_F;
    float th=a*d/CUTOFF;
    float sn=sinf(th), cs=cosf(th);
    float drb = cc*((a/CUTOFF)*cs*d - sn)*inv*inv;
    acc = fmaf(g_rbf[(size_t)e*20+k], drb, acc);
  }
  g_d += acc*tie;
  size_t b3=(size_t)e*3, b8=(size_t)e*8;
  float ux=bv[b3+0]*inv, uy=bv[b3+1]*inv, uz=bv[b3+2]*inv;
  const float s3=1.7320508075688772f;
  float G1y=g_l8[b8+0], G1z=g_l8[b8+1], G1x=g_l8[b8+2];
  float A=g_l8[b8+3], B=g_l8[b8+4], Cq=g_l8[b8+5], D=g_l8[b8+6], F=g_l8[b8+7];
  float gux = G1x + s3*(uy*A + uz*D + ux*F);
  float guy = G1y + s3*(ux*A + uz*B) - s3*uy*F;
  float guz = G1z + s3*uy*B + 3.f*uz*Cq + s3*ux*D;
  float ud = ux*gux+uy*guy+uz*guz;
  float gbx = (gux-ux*ud)*inv + g_d*ux;
  float gby = (guy-uy*ud)*inv + g_d*uy;
  float gbz = (guz-uz*ud)*inv + g_d*uz;
  float fx = gbx + eg[b3+0];
  float fy = gby + eg[b3+1];
  float fz = gbz + eg[b3+2];
  int s=eidx[e], t=eidx[E+e];
  atomicAdd(&force[s*3+0],-fx); atomicAdd(&force[s*3+1],-fy); atomicAdd(&force[s*3+2],-fz);
  atomicAdd(&force[t*3+0], fx); atomicAdd(&force[t*3+1], fy); atomicAdd(&force[t*3+2], fz);
}

// ================================================================ launch
extern "C" void kernel_launch(void* const* d_in, const int* in_sizes, int n_in,
                              void* d_out, int out_size, void* d_ws, size_t ws_size,
                              hipStream_t stream)
{
  const float* pos   = (const float*)d_in[0];
  const float* eattr = (const float*)d_in[1];
  const float* eagr  = (const float*)d_in[2];
  const float* W_mat = (const float*)d_in[3];
  const float* b_mat = (const float*)d_in[4];
  const float* W_emb = (const float*)d_in[5];
  const float* b_emb = (const float*)d_in[6];
  const float* Wv    = (const float*)d_in[7];
  const float* Wr    = (const float*)d_in[8];
  const float* Wx    = (const float*)d_in[9];
  const float* w_out = (const float*)d_in[10];
  const int* eidx    = (const int*)d_in[11];
  const int* nei     = (const int*)d_in[12];
  const int* abatch  = (const int*)d_in[13];

  const int E  = in_sizes[1]/169;
  const int LE = in_sizes[12]/2;

  float* p = (float*)d_ws;
  auto alloc=[&](size_t n){ float* q=p; p+=n; return q; };
  float* bv    = alloc((size_t)3*E);
  float* d_a   = alloc(E);
  float* env_a = alloc(E);
  float* l8    = alloc((size_t)8*E);
  float* rbf   = alloc((size_t)20*E);
  float* g_env = alloc(E);
  float* g_l8  = alloc((size_t)8*E);
  float* eg    = alloc((size_t)3*E);
  float* Wvs   = alloc(1024);
  float* h_pre = alloc((size_t)128*E);
  float* x0    = alloc((size_t)128*E);
  float* x1    = alloc((size_t)128*E);
  float* x2    = alloc((size_t)128*E);
  float* apre0 = alloc((size_t)128*E);
  float* apre1 = alloc((size_t)128*E);
  float* apre2 = alloc((size_t)128*E);
  float* bufA  = alloc((size_t)128*E);   // m / x3 / g_agg target
  float* bufB  = alloc((size_t)128*E);   // agg / g_agg / g_hpre
  float* g_x   = alloc((size_t)128*E);
  float* g_rbf = alloc((size_t)20*E);    // zero-region start
  int* ip = (int*)p;
  int* deg_dst = ip; ip+=E;
  int* deg_src = ip; ip+=E;
  int* cur_dst = ip; ip+=E;
  int* cur_src = ip; ip+=E;              // zero-region end (24E * 4B)
  int* rp_dst  = ip; ip+=E+1;
  int* rp_src  = ip; ip+=E+1;
  int* col_dst = ip; ip+=LE;
  int* col_src = ip; ip+=LE;
  float* vecb  = apre0;                  // (E x 169, ld 172) aliases apre0/1

  float* results = (float*)d_out;
  float* force   = results + 64;

  hipMemsetAsync(d_out, 0, (size_t)out_size*sizeof(float), stream);
  hipMemsetAsync(g_rbf, 0, (size_t)24*E*sizeof(float), stream);

  float* xsm[4]   = {x0,x1,x2,bufA};
  float* apres[3] = {apre0,apre1,apre2};

  const int gE  = (E+255)/256;
  const int gLE = (LE+255)/256;
  const int gW  = (E+3)/4;          // one wave per edge (1-row kernels)
  const int gW4 = (E+15)/16;        // 4 waves x 4 rows per block (convgather)
  const int gW8 = (E+31)/32;        // 4 waves x 8 rows per block (gather1)
  dim3 gg((E+63)/64, 1);

  // forward
  xg_geom<<<gE,256,0,stream>>>(pos, eidx, E, bv, d_a, env_a, l8, rbf);
  xg_wvs<<<1,128,0,stream>>>(Wv, Wvs);
  xg_hist<<<gLE,256,0,stream>>>(nei, LE, deg_dst, deg_src);
  xg_scan2<<<2,1024,0,stream>>>(deg_dst, rp_dst, deg_src, rp_src, E);
  xg_fill<<<gLE,256,0,stream>>>(nei, LE, rp_dst, cur_dst, col_dst, rp_src, cur_src, col_src);

  xg_gemm<PRE_SCALE_ROW,POST_BIAS,false><<<gg,256,0,stream>>>(
      eattr,169,169, W_mat,128,128, h_pre,128, env_a,nullptr,nullptr, b_mat,
      nullptr,nullptr,nullptr, E);
  xg_gemm<PRE_SILU,POST_X0,false><<<gg,256,0,stream>>>(
      h_pre,128,128, W_emb,128,128, x0,128, nullptr,nullptr,nullptr, b_emb,
      l8,Wvs,nullptr, E);

  for (int l=0;l<3;l++) {
    // m = silu(rbf@Wr_l) * x_l  (fused gate+mul)
    xg_gemm<PRE_NONE,POST_GATE,false><<<gg,256,0,stream>>>(
        rbf,20,20, Wr+(size_t)l*2560,128,128, bufA,128,
        nullptr,nullptr, xsm[l], nullptr,nullptr,nullptr,nullptr, E);
    xg_gather1<<<gW8,256,0,stream>>>(bufA, rp_dst, col_dst, bufB, E);
    xg_gemm<PRE_NONE,POST_CONV,false><<<gg,256,0,stream>>>(
        bufB,128,128, Wx+(size_t)l*16384,128,128, apres[l],128,
        nullptr,nullptr, xsm[l], nullptr,nullptr,nullptr, xsm[l+1], E);
  }

  xg_out<<<512,256,0,stream>>>(bufA, env_a, w_out, eidx, abatch, g_env, results, E);

  // backward
  xg_gxinit<<<(int)(((size_t)E*128+255)/256),256,0,stream>>>(env_a, w_out, g_x, E);
  for (int l=2;l>=0;l--) {
    xg_gemm<PRE_MUL_SILUD,POST_PLAIN,true><<<gg,256,0,stream>>>(
        g_x,128,128, Wx+(size_t)l*16384,128,128, bufB,128,
        nullptr, apres[l], nullptr, nullptr,nullptr,nullptr,nullptr, E);
    xg_convgather<<<gW4,256,0,stream>>>(bufB, rp_src, col_src, xsm[l], g_x,
                                        rbf, g_rbf, Wr+(size_t)l*2560, E);
  }
  xg_vpath<<<gW,256,0,stream>>>(g_x, l8, Wvs, g_l8, E);
  xg_gemm<PRE_NONE,POST_MUL_SILUD,true><<<gg,256,0,stream>>>(
      g_x,128,128, W_emb,128,128, bufB,128, nullptr,nullptr, h_pre,
      nullptr,nullptr,nullptr,nullptr, E);
  dim3 g8((E+63)/64, 2);
  xg_gemm<PRE_NONE,POST_PLAIN,true><<<g8,256,0,stream>>>(
      bufB,128,128, W_mat,128,169, vecb,172,
      nullptr,nullptr,nullptr,nullptr,nullptr,nullptr,nullptr, E);
  xg_eattrbwd<<<gW,256,0,stream>>>(vecb, eattr, eagr, env_a, g_env, eg, E);
  xg_force<<<gE,256,0,stream>>>(bv, d_a, g_env, g_rbf, g_l8, eg, eidx, force, E);
}

// Round 5
// 3374.500 us; speedup vs baseline: 1.0510x; 1.0142x over previous
//
#include <hip/hip_runtime.h>
#include <cstdint>

// Round 8: convgather split at the phase boundary after two failed MLP tunings
// (R3: 8-row 326us; R4: 4-row x2 279us vs R2 simple 230us -- more outstanding
// loads never helped; latency-bound gather serialized against VALU epilogue
// within each wave).
// - bwd per layer: GEMM -> xg_gather1 (pure gather, bufB->bufA) ->
//   xg_convstream (pure streaming epilogue: gate recompute, g_x update, g_rbf)
// - bufA is free during backward (xg_out consumed x3 before it)
// GEMM / fwd path unchanged.

#define CUTOFF 5.0f
#define PI_F 3.14159265358979323846f

__device__ __forceinline__ float siluf(float v){ float s=1.f/(1.f+__expf(-v)); return v*s; }
__device__ __forceinline__ float silud(float v){ float s=1.f/(1.f+__expf(-v)); return s*(1.f+v*(1.f-s)); }

// ---- DPP wave64 sum: result valid in lane 63 (VALU pipe, no LDS traffic)
template<int CTRL>
__device__ __forceinline__ float dpp_radd(float x){
  int y = __builtin_amdgcn_update_dpp(0, __float_as_int(x), CTRL, 0xf, 0xf, false);
  return x + __int_as_float(y);
}
__device__ __forceinline__ float wave_sum63(float x){
  x = dpp_radd<0x111>(x);  // row_shr:1
  x = dpp_radd<0x112>(x);  // row_shr:2
  x = dpp_radd<0x114>(x);  // row_shr:4
  x = dpp_radd<0x118>(x);  // row_shr:8
  x = dpp_radd<0x142>(x);  // row_bcast:15
  x = dpp_radd<0x143>(x);  // row_bcast:31 -> lane63 has full sum
  return x;
}

constexpr int PRE_NONE=0, PRE_SCALE_ROW=1, PRE_SILU=2, PRE_MUL_SILUD=3;
constexpr int POST_PLAIN=0, POST_BIAS=1, POST_GATE=2, POST_X0=3, POST_CONV=4, POST_MUL_SILUD=5;

// ---------------------------------------------------------------- GEMM
template<int PRE, int POST, bool BT>
__global__ __launch_bounds__(256) void xg_gemm(
    const float* __restrict__ A, int ldA, int K,
    const float* __restrict__ B, int ldB, int N,
    float* __restrict__ C, int ldC,
    const float* __restrict__ rowscale,   // PRE_SCALE_ROW
    const float* __restrict__ auxA,       // PRE_MUL_SILUD  (ld 128)
    const float* __restrict__ auxC,       // POST_CONV / POST_GATE (x_l) / POST_MUL_SILUD (h_pre)
    const float* __restrict__ bias,       // POST_BIAS / POST_X0
    const float* __restrict__ l8g,        // POST_X0 (E x 8 row-major)
    const float* __restrict__ Wvsg,       // POST_X0 (8 x 128)
    float* __restrict__ C2,               // POST_CONV x_{l+1}
    int E)
{
  __shared__ float Alds[64][36];          // 36-float row stride: 144B, 16B aligned
  __shared__ float Blds[32][132];
  __shared__ float l8s[8][64];
  __shared__ float WvsS[8][128];

  const int tid = threadIdx.x;
  const int e0 = blockIdx.x*64;
  const int n0 = blockIdx.y*128;

  if constexpr (POST==POST_X0) {
    for (int i=tid;i<1024;i+=256) WvsS[i>>7][i&127] = Wvsg[i];
    for (int i=tid;i<512;i+=256) {
      int r=i>>3, c=i&7; int e=e0+r;
      l8s[c][r] = (e<E)? l8g[(size_t)e*8+c] : 0.f;
    }
  }

  const int ty = tid>>5, tx = tid&31;
  float acc[8][4];
  #pragma unroll
  for (int i=0;i<8;i++){acc[i][0]=0.f;acc[i][1]=0.f;acc[i][2]=0.f;acc[i][3]=0.f;}

  for (int k0=0;k0<K;k0+=32) {
    __syncthreads();
    { // A tile 64x32
      const int kk = tid&31, rb = tid>>5;
      #pragma unroll
      for (int p=0;p<8;p++) {
        int r = rb + p*8;
        int e = e0+r, k = k0+kk;
        float v = 0.f;
        if (e<E && k<K) {
          v = A[(size_t)e*ldA + k];
          if constexpr (PRE==PRE_SCALE_ROW) v *= rowscale[e];
          if constexpr (PRE==PRE_SILU)      v = siluf(v);
          if constexpr (PRE==PRE_MUL_SILUD) v *= silud(auxA[(size_t)e*128+k]);
        }
        Alds[r][kk] = v;
      }
    }
    if constexpr (!BT) { // B row-major KxN
      const int n = tid&127, kb = tid>>7;
      #pragma unroll
      for (int p=0;p<16;p++) {
        int kk = kb + p*2;
        int k = k0+kk, nn = n0+n;
        Blds[kk][n] = (k<K && nn<N) ? B[(size_t)k*ldB+nn] : 0.f;
      }
    } else {             // B = W^T, W row-major NxK (ldB)
      const int kk = tid&31, nb = tid>>5;
      #pragma unroll
      for (int p=0;p<16;p++) {
        int n = nb + p*8;
        int k = k0+kk, nn = n0+n;
        Blds[kk][n] = (k<K && nn<N) ? B[(size_t)nn*ldB+k] : 0.f;
      }
    }
    __syncthreads();
    #pragma unroll
    for (int kk4=0;kk4<8;kk4++) {
      float4 b0 = *(const float4*)&Blds[kk4*4+0][tx*4];
      float4 b1 = *(const float4*)&Blds[kk4*4+1][tx*4];
      float4 b2 = *(const float4*)&Blds[kk4*4+2][tx*4];
      float4 b3 = *(const float4*)&Blds[kk4*4+3][tx*4];
      #pragma unroll
      for (int i=0;i<8;i++) {
        float4 a = *(const float4*)&Alds[ty*8+i][kk4*4];
        acc[i][0] = fmaf(a.x,b0.x,acc[i][0]);
        acc[i][1] = fmaf(a.x,b0.y,acc[i][1]);
        acc[i][2] = fmaf(a.x,b0.z,acc[i][2]);
        acc[i][3] = fmaf(a.x,b0.w,acc[i][3]);
        acc[i][0] = fmaf(a.y,b1.x,acc[i][0]);
        acc[i][1] = fmaf(a.y,b1.y,acc[i][1]);
        acc[i][2] = fmaf(a.y,b1.z,acc[i][2]);
        acc[i][3] = fmaf(a.y,b1.w,acc[i][3]);
        acc[i][0] = fmaf(a.z,b2.x,acc[i][0]);
        acc[i][1] = fmaf(a.z,b2.y,acc[i][1]);
        acc[i][2] = fmaf(a.z,b2.z,acc[i][2]);
        acc[i][3] = fmaf(a.z,b2.w,acc[i][3]);
        acc[i][0] = fmaf(a.w,b3.x,acc[i][0]);
        acc[i][1] = fmaf(a.w,b3.y,acc[i][1]);
        acc[i][2] = fmaf(a.w,b3.z,acc[i][2]);
        acc[i][3] = fmaf(a.w,b3.w,acc[i][3]);
      }
    }
  }

  const int cbase = n0 + tx*4;
  #pragma unroll
  for (int i=0;i<8;i++) {
    int e = e0 + ty*8 + i;
    if (e>=E) break;
    size_t ci = (size_t)e*ldC + cbase;
    float4 v = make_float4(acc[i][0],acc[i][1],acc[i][2],acc[i][3]);
    if constexpr (POST==POST_BIAS) {
      v.x+=bias[cbase]; v.y+=bias[cbase+1]; v.z+=bias[cbase+2]; v.w+=bias[cbase+3];
      *(float4*)&C[ci]=v;
    } else if constexpr (POST==POST_GATE) { // m = silu(acc) * x_l
      float4 xl4 = *(const float4*)&auxC[(size_t)e*128 + cbase];
      v.x=siluf(v.x)*xl4.x; v.y=siluf(v.y)*xl4.y;
      v.z=siluf(v.z)*xl4.z; v.w=siluf(v.w)*xl4.w;
      *(float4*)&C[ci]=v;
    } else if constexpr (POST==POST_X0) {
      float vp0=0.f,vp1=0.f,vp2=0.f,vp3=0.f;
      int r = ty*8+i;
      #pragma unroll
      for (int c=0;c<8;c++){
        float lc = l8s[c][r];
        vp0=fmaf(lc,WvsS[c][cbase+0],vp0); vp1=fmaf(lc,WvsS[c][cbase+1],vp1);
        vp2=fmaf(lc,WvsS[c][cbase+2],vp2); vp3=fmaf(lc,WvsS[c][cbase+3],vp3);
      }
      v.x += bias[cbase+0] + siluf(vp0);
      v.y += bias[cbase+1] + siluf(vp1);
      v.z += bias[cbase+2] + siluf(vp2);
      v.w += bias[cbase+3] + siluf(vp3);
      *(float4*)&C[ci]=v;
    } else if constexpr (POST==POST_CONV) {
      *(float4*)&C[ci]=v; // apre_l
      float4 xl = *(const float4*)&auxC[(size_t)e*128 + cbase];
      float4 o = make_float4(xl.x+siluf(v.x), xl.y+siluf(v.y),
                             xl.z+siluf(v.z), xl.w+siluf(v.w));
      *(float4*)&C2[ci]=o; // x_{l+1}
    } else if constexpr (POST==POST_MUL_SILUD) {
      float4 a4 = *(const float4*)&auxC[(size_t)e*128 + cbase];
      v.x*=silud(a4.x); v.y*=silud(a4.y); v.z*=silud(a4.z); v.w*=silud(a4.w);
      *(float4*)&C[ci]=v;
    } else { // POST_PLAIN
      if (cbase+3 < N) { *(float4*)&C[ci]=v; }
      else {
        float vv[4]={v.x,v.y,v.z,v.w};
        #pragma unroll
        for (int j=0;j<4;j++) if (cbase+j<N) C[ci+j]=vv[j];
      }
    }
  }
}

// ---------------------------------------------------------------- geometry
__global__ __launch_bounds__(256) void xg_geom(const float* __restrict__ pos,
  const int* __restrict__ eidx, int E,
  float* __restrict__ bv, float* __restrict__ d_a, float* __restrict__ env_a,
  float* __restrict__ l8, float* __restrict__ rbf)
{
  int e = blockIdx.x*256+threadIdx.x;
  if (e>=E) return;
  int s = eidx[e], t = eidx[E+e];
  float bx = pos[s*3+0]-pos[t*3+0];
  float by = pos[s*3+1]-pos[t*3+1];
  float bz = pos[s*3+2]-pos[t*3+2];
  float d = sqrtf(bx*bx+by*by+bz*bz + 1e-12f);
  bv[(size_t)e*3+0]=bx; bv[(size_t)e*3+1]=by; bv[(size_t)e*3+2]=bz;
  d_a[e]=d;
  float xx = d/CUTOFF;
  float x2=xx*xx, x4=x2*x2, x5=x4*xx, x6=x5*xx, x7=x6*xx;
  env_a[e] = (d<CUTOFF)? (1.f-21.f*x5+35.f*x6-15.f*x7) : 0.f;
  float inv = 1.f/d;
  float ux=bx*inv, uy=by*inv, uz=bz*inv;
  const float s3 = 1.7320508075688772f;
  size_t b8=(size_t)e*8;
  l8[b8+0]=uy; l8[b8+1]=uz; l8[b8+2]=ux;
  l8[b8+3]=s3*ux*uy; l8[b8+4]=s3*uy*uz;
  l8[b8+5]=0.5f*(3.f*uz*uz-1.f);
  l8[b8+6]=s3*ux*uz; l8[b8+7]=0.5f*s3*(ux*ux-uy*uy);
  float ds = fmaxf(d, 1e-6f);
  const float cc = 0.632455532033676f; // sqrt(2/5)
  #pragma unroll
  for (int k=0;k<20;k++){
    float th = ((k+1)*PI_F)*ds/CUTOFF;
    rbf[(size_t)e*20+k] = cc*sinf(th)/ds;
  }
}

// tile-summed Wv: Wvs[8][128]
__global__ void xg_wvs(const float* __restrict__ Wv, float* __restrict__ Wvs){
  int h=threadIdx.x;
  #pragma unroll
  for (int c=0;c<3;c++){
    float s=0.f;
    for (int t=0;t<64;t++) s+=Wv[(size_t)(t*3+c)*128+h];
    Wvs[c*128+h]=s;
  }
  #pragma unroll
  for (int c=0;c<5;c++){
    float s=0.f;
    for (int t=0;t<32;t++) s+=Wv[(size_t)(192+t*5+c)*128+h];
    Wvs[(3+c)*128+h]=s;
  }
}

// ---------------------------------------------------------------- CSR build
__global__ __launch_bounds__(256) void xg_hist(const int* __restrict__ nei, int LE,
                                               int* deg_dst, int* deg_src){
  int i=blockIdx.x*256+threadIdx.x;
  if (i>=LE) return;
  atomicAdd(&deg_src[nei[i]],1);
  atomicAdd(&deg_dst[nei[LE+i]],1);
}

__global__ __launch_bounds__(1024) void xg_scan2(const int* __restrict__ degA, int* __restrict__ rpA,
                                                 const int* __restrict__ degB, int* __restrict__ rpB, int n){
  const int* deg = (blockIdx.x==0)? degA : degB;
  int* rp = (blockIdx.x==0)? rpA : rpB;
  __shared__ int wsum[16];
  int tid=threadIdx.x, lane=tid&63, wid=tid>>6;
  int carry=0;
  for (int base=0;base<n;base+=1024){
    int i=base+tid;
    int v=(i<n)?deg[i]:0;
    int x=v;
    #pragma unroll
    for (int off=1;off<64;off<<=1){int y=__shfl_up(x,off); if(lane>=off)x+=y;}
    if (lane==63) wsum[wid]=x;
    __syncthreads();
    if (wid==0 && lane<16){
      int s=wsum[lane];
      #pragma unroll
      for (int off=1;off<16;off<<=1){int y=__shfl_up(s,off); if(lane>=off)s+=y;}
      wsum[lane]=s;
    }
    __syncthreads();
    int woff=(wid==0)?0:wsum[wid-1];
    if (i<n) rp[i]=carry+woff+x-v;
    carry+=wsum[15];
    __syncthreads();
  }
  if (tid==0) rp[n]=carry;
}

__global__ __launch_bounds__(256) void xg_fill(const int* __restrict__ nei, int LE,
    const int* __restrict__ rp_dst, int* cur_dst, int* col_dst,
    const int* __restrict__ rp_src, int* cur_src, int* col_src){
  int i=blockIdx.x*256+threadIdx.x;
  if (i>=LE) return;
  int s=nei[i], d=nei[LE+i];
  int pd = rp_dst[d] + atomicAdd(&cur_dst[d],1);
  col_dst[pd] = s;  // store le_src for fwd gather
  int ps = rp_src[s] + atomicAdd(&cur_src[s],1);
  col_src[ps] = d;  // store le_dst for bwd gather
}

// ---------------------------------------------------------------- gathers
// gather1: 8 rows per wave, float2 lanes, branchless predication,
// next-iter col[] indices prefetched ahead of FMA consume.
__global__ __launch_bounds__(256) void xg_gather1(const float* __restrict__ g,
  const int* __restrict__ rp, const int* __restrict__ col,
  float* __restrict__ out, int E)
{
  const float2* g2 = (const float2*)g;
  float2* out2 = (float2*)out;
  int w=(blockIdx.x*256+threadIdx.x)>>6, lane=threadIdx.x&63;
  int r0 = w*8;
  if (r0>=E) return;
  int s[8], e[8];
  #pragma unroll
  for (int j=0;j<8;j++){
    int r=r0+j;
    s[j]=(r<E)?rp[r]:0; e[j]=(r<E)?rp[r+1]:0;
  }
  float2 acc[8];
  #pragma unroll
  for (int j=0;j<8;j++) acc[j]=make_float2(0.f,0.f);

  int c[8]; float m[8];
  int live=0;
  #pragma unroll
  for (int j=0;j<8;j++){
    bool a = s[j]<e[j]; live |= (int)a;
    c[j]=a?col[s[j]]:0; m[j]=a?1.f:0.f;
  }
  while (live){
    float2 v[8];
    #pragma unroll
    for (int j=0;j<8;j++) v[j]=g2[(size_t)c[j]*64+lane];
    // prefetch next-iter indices while v loads are in flight
    int cn[8]; float mn[8];
    live=0;
    #pragma unroll
    for (int j=0;j<8;j++){
      s[j]++;
      bool a = s[j]<e[j]; live |= (int)a;
      cn[j]=a?col[s[j]]:0; mn[j]=a?1.f:0.f;
    }
    #pragma unroll
    for (int j=0;j<8;j++){
      acc[j].x=fmaf(v[j].x,m[j],acc[j].x); acc[j].y=fmaf(v[j].y,m[j],acc[j].y);
      c[j]=cn[j]; m[j]=mn[j];
    }
  }
  #pragma unroll
  for (int j=0;j<8;j++){
    int r=r0+j;
    if (r<E) out2[(size_t)r*64+lane]=acc[j];
  }
}

// streaming conv-bwd epilogue: G (gathered, coalesced), gate/gpre recomputed;
// g_x += gate*G; g_rbf[e][k] = sum_h (x_l*G*silu'(gpre))[h]*Wr[k][h] via DPP.
// All accesses sequential; 4 rows/wave.
__global__ __launch_bounds__(256) void xg_convstream(const float* __restrict__ G,
  const int* /*unused*/, const int* /*unused2*/,
  const float* __restrict__ xl, float* __restrict__ g_x,
  const float* __restrict__ rbf, float* __restrict__ g_rbf,
  const float* __restrict__ Wr_l, int E)
{
  __shared__ float wr[2560];
  for (int i=threadIdx.x;i<2560;i+=256) wr[i]=Wr_l[i];
  __syncthreads();
  const float2* G2 = (const float2*)G;
  const float2* xl2 = (const float2*)xl;
  float2* gx2 = (float2*)g_x;
  const float2* wr2 = (const float2*)wr;
  int w=(blockIdx.x*256+threadIdx.x)>>6, lane=threadIdx.x&63;
  int r0 = w*4;
  if (r0>=E) return;
  #pragma unroll
  for (int j=0;j<4;j++){
    int row=r0+j;
    if (row>=E) break;
    size_t b=(size_t)row*64+lane;
    float2 a = G2[b];          // streaming, coalesced
    float2 x2v = xl2[b];
    float rk[20];
    #pragma unroll
    for (int k=0;k<20;k++) rk[k]=rbf[(size_t)row*20+k];
    float gp0=0.f,gp1=0.f;
    #pragma unroll
    for (int k=0;k<20;k++){
      float2 w2=wr2[k*64+lane];
      gp0=fmaf(rk[k],w2.x,gp0); gp1=fmaf(rk[k],w2.y,gp1);
    }
    float ss0=1.f/(1.f+__expf(-gp0)), ss1=1.f/(1.f+__expf(-gp1));
    float gate0=gp0*ss0, gate1=gp1*ss1;
    float sd0=ss0*(1.f+gp0*(1.f-ss0)), sd1=ss1*(1.f+gp1*(1.f-ss1));
    float gg0 = x2v.x*a.x*sd0, gg1 = x2v.y*a.y*sd1;
    float2 gx = gx2[b];
    gx.x += gate0*a.x; gx.y += gate1*a.y;
    gx2[b] = gx;
    #pragma unroll
    for (int k=0;k<20;k++){
      float2 w2=wr2[k*64+lane];
      float v = wave_sum63(fmaf(gg0, w2.x, gg1*w2.y));
      if (lane==63) g_rbf[(size_t)row*20+k] += v;
    }
  }
}

// ---------------------------------------------------------------- outputs
__global__ __launch_bounds__(256) void xg_out(const float* __restrict__ x3,
  const float* __restrict__ env_a, const float* __restrict__ w_out,
  const int* __restrict__ eidx, const int* __restrict__ abatch,
  float* __restrict__ g_env, float* __restrict__ results, int E)
{
  __shared__ float bins[64];
  __shared__ float wsh[128];
  int tid=threadIdx.x;
  if (tid<64) bins[tid]=0.f;
  if (tid<128) wsh[tid]=w_out[tid];
  __syncthreads();
  int lane=tid&63;
  int gw = blockIdx.x*4 + (tid>>6);
  int stride = gridDim.x*4;
  for (int e=gw; e<E; e+=stride){
    size_t b=(size_t)e*128;
    float v = wave_sum63(x3[b+lane]*wsh[lane] + x3[b+lane+64]*wsh[lane+64]);
    if (lane==63){
      g_env[e]=v;
      float ee=v*env_a[e];
      if (ee!=0.f) atomicAdd(&bins[abatch[eidx[e]]], ee);
    }
  }
  __syncthreads();
  if (tid<64){ float bb=bins[tid]; if (bb!=0.f) atomicAdd(&results[tid], bb); }
}

__global__ __launch_bounds__(256) void xg_gxinit(const float* __restrict__ env_a,
  const float* __restrict__ w_out, float* __restrict__ g_x, int E){
  size_t i = (size_t)blockIdx.x*256+threadIdx.x;
  if (i >= (size_t)E*128) return;
  int e = (int)(i>>7), h = (int)(i&127);
  g_x[i] = env_a[e]*w_out[h];
}

// rsh path bwd: g_l8[c] = sum_h g_x0[h]*silu'(vpre[h])*Wvs[c][h]
__global__ __launch_bounds__(256) void xg_vpath(const float* __restrict__ g_x,
  const float* __restrict__ l8, const float* __restrict__ Wvs,
  float* __restrict__ g_l8, int E)
{
  __shared__ float W[1024];
  for (int i=threadIdx.x;i<1024;i+=256) W[i]=Wvs[i];
  __syncthreads();
  int gw=(blockIdx.x*256+threadIdx.x)>>6, lane=threadIdx.x&63;
  if (gw>=E) return;
  float l[8];
  #pragma unroll
  for (int c=0;c<8;c++) l[c]=l8[(size_t)gw*8+c];
  float vp0=0.f, vp1=0.f;
  #pragma unroll
  for (int c=0;c<8;c++){ vp0=fmaf(l[c],W[c*128+lane],vp0); vp1=fmaf(l[c],W[c*128+lane+64],vp1); }
  size_t b=(size_t)gw*128;
  float gv0 = g_x[b+lane]*silud(vp0);
  float gv1 = g_x[b+lane+64]*silud(vp1);
  #pragma unroll
  for (int c=0;c<8;c++){
    float v = wave_sum63(fmaf(gv0, W[c*128+lane], gv1*W[c*128+lane+64]));
    if (lane==63) g_l8[(size_t)gw*8+c] = v;
  }
}

// eattr path: g_env += vec.eattr; edge_grads[k] = env * vec . eagrad[:,k,:]
__global__ __launch_bounds__(256) void xg_eattrbwd(const float* __restrict__ vecb,
  const float* __restrict__ eattr, const float* __restrict__ eagr,
  const float* __restrict__ env_a, float* __restrict__ g_env,
  float* __restrict__ eg, int E)
{
  int gw=(blockIdx.x*256+threadIdx.x)>>6, lane=threadIdx.x&63;
  if (gw>=E) return;
  const float* vr = vecb + (size_t)gw*172;
  const float* ar = eattr + (size_t)gw*169;
  const float* gr = eagr + (size_t)gw*507;
  float se=0.f,e0=0.f,e1=0.f,e2=0.f;
  for (int f=lane; f<169; f+=64){
    float v=vr[f];
    se=fmaf(v,ar[f],se);
    e0=fmaf(v,gr[f],e0);
    e1=fmaf(v,gr[169+f],e1);
    e2=fmaf(v,gr[338+f],e2);
  }
  se=wave_sum63(se); e0=wave_sum63(e0); e1=wave_sum63(e1); e2=wave_sum63(e2);
  if (lane==63){
    g_env[gw] += se;
    float en = env_a[gw];
    eg[(size_t)gw*3+0]=e0*en; eg[(size_t)gw*3+1]=e1*en; eg[(size_t)gw*3+2]=e2*en;
  }
}

// final: g_d (env + rbf paths), g_u -> g_bv, + edge_grads, scatter to force
__global__ __launch_bounds__(256) void xg_force(const float* __restrict__ bv,
  const float* __restrict__ d_a, const float* __restrict__ g_env,
  const float* __restrict__ g_rbf, const float* __restrict__ g_l8,
  const float* __restrict__ eg, const int* __restrict__ eidx,
  float* __restrict__ force, int E)
{
  int e = blockIdx.x*256+threadIdx.x;
  if (e>=E) return;
  float d = d_a[e];
  float inv = 1.f/d;
  float xx = d/CUTOFF;
  float x2=xx*xx, x4=x2*x2, x5=x4*xx, x6=x5*xx;
  float g_d = g_env[e] * ((d<CUTOFF)? ((-105.f*x4+210.f*x5-105.f*x6)/CUTOFF) : 0.f);
  const float cc=0.632455532033676f;
  float tie = (d>1e-6f)?1.f:0.5f;
  float acc=0.f;
  #pragma unroll
  for (int k=0;k<20;k++){
    float a=(k+1)*PI_F;
    float th=a*d/CUTOFF;
    float sn=sinf(th), cs=cosf(th);
    float drb = cc*((a/CUTOFF)*cs*d - sn)*inv*inv;
    acc = fmaf(g_rbf[(size_t)e*20+k], drb, acc);
  }
  g_d += acc*tie;
  size_t b3=(size_t)e*3, b8=(size_t)e*8;
  float ux=bv[b3+0]*inv, uy=bv[b3+1]*inv, uz=bv[b3+2]*inv;
  const float s3=1.7320508075688772f;
  float G1y=g_l8[b8+0], G1z=g_l8[b8+1], G1x=g_l8[b8+2];
  float A=g_l8[b8+3], B=g_l8[b8+4], Cq=g_l8[b8+5], D=g_l8[b8+6], F=g_l8[b8+7];
  float gux = G1x + s3*(uy*A + uz*D + ux*F);
  float guy = G1y + s3*(ux*A + uz*B) - s3*uy*F;
  float guz = G1z + s3*uy*B + 3.f*uz*Cq + s3*ux*D;
  float ud = ux*gux+uy*guy+uz*guz;
  float gbx = (gux-ux*ud)*inv + g_d*ux;
  float gby = (guy-uy*ud)*inv + g_d*uy;
  float gbz = (guz-uz*ud)*inv + g_d*uz;
  float fx = gbx + eg[b3+0];
  float fy = gby + eg[b3+1];
  float fz = gbz + eg[b3+2];
  int s=eidx[e], t=eidx[E+e];
  atomicAdd(&force[s*3+0],-fx); atomicAdd(&force[s*3+1],-fy); atomicAdd(&force[s*3+2],-fz);
  atomicAdd(&force[t*3+0], fx); atomicAdd(&force[t*3+1], fy); atomicAdd(&force[t*3+2], fz);
}

// ================================================================ launch
extern "C" void kernel_launch(void* const* d_in, const int* in_sizes, int n_in,
                              void* d_out, int out_size, void* d_ws, size_t ws_size,
                              hipStream_t stream)
{
  const float* pos   = (const float*)d_in[0];
  const float* eattr = (const float*)d_in[1];
  const float* eagr  = (const float*)d_in[2];
  const float* W_mat = (const float*)d_in[3];
  const float* b_mat = (const float*)d_in[4];
  const float* W_emb = (const float*)d_in[5];
  const float* b_emb = (const float*)d_in[6];
  const float* Wv    = (const float*)d_in[7];
  const float* Wr    = (const float*)d_in[8];
  const float* Wx    = (const float*)d_in[9];
  const float* w_out = (const float*)d_in[10];
  const int* eidx    = (const int*)d_in[11];
  const int* nei     = (const int*)d_in[12];
  const int* abatch  = (const int*)d_in[13];

  const int E  = in_sizes[1]/169;
  const int LE = in_sizes[12]/2;

  float* p = (float*)d_ws;
  auto alloc=[&](size_t n){ float* q=p; p+=n; return q; };
  float* bv    = alloc((size_t)3*E);
  float* d_a   = alloc(E);
  float* env_a = alloc(E);
  float* l8    = alloc((size_t)8*E);
  float* rbf   = alloc((size_t)20*E);
  float* g_env = alloc(E);
  float* g_l8  = alloc((size_t)8*E);
  float* eg    = alloc((size_t)3*E);
  float* Wvs   = alloc(1024);
  float* h_pre = alloc((size_t)128*E);
  float* x0    = alloc((size_t)128*E);
  float* x1    = alloc((size_t)128*E);
  float* x2    = alloc((size_t)128*E);
  float* apre0 = alloc((size_t)128*E);
  float* apre1 = alloc((size_t)128*E);
  float* apre2 = alloc((size_t)128*E);
  float* bufA  = alloc((size_t)128*E);   // m / x3 / G (bwd gather target)
  float* bufB  = alloc((size_t)128*E);   // agg / g_agg / g_hpre
  float* g_x   = alloc((size_t)128*E);
  float* g_rbf = alloc((size_t)20*E);    // zero-region start
  int* ip = (int*)p;
  int* deg_dst = ip; ip+=E;
  int* deg_src = ip; ip+=E;
  int* cur_dst = ip; ip+=E;
  int* cur_src = ip; ip+=E;              // zero-region end (24E * 4B)
  int* rp_dst  = ip; ip+=E+1;
  int* rp_src  = ip; ip+=E+1;
  int* col_dst = ip; ip+=LE;
  int* col_src = ip; ip+=LE;
  float* vecb  = apre0;                  // (E x 169, ld 172) aliases apre0/1

  float* results = (float*)d_out;
  float* force   = results + 64;

  hipMemsetAsync(d_out, 0, (size_t)out_size*sizeof(float), stream);
  hipMemsetAsync(g_rbf, 0, (size_t)24*E*sizeof(float), stream);

  float* xsm[4]   = {x0,x1,x2,bufA};
  float* apres[3] = {apre0,apre1,apre2};

  const int gE  = (E+255)/256;
  const int gLE = (LE+255)/256;
  const int gW  = (E+3)/4;          // one wave per edge (1-row kernels)
  const int gW4 = (E+15)/16;        // 4 waves x 4 rows per block (convstream)
  const int gW8 = (E+31)/32;        // 4 waves x 8 rows per block (gather1)
  dim3 gg((E+63)/64, 1);

  // forward
  xg_geom<<<gE,256,0,stream>>>(pos, eidx, E, bv, d_a, env_a, l8, rbf);
  xg_wvs<<<1,128,0,stream>>>(Wv, Wvs);
  xg_hist<<<gLE,256,0,stream>>>(nei, LE, deg_dst, deg_src);
  xg_scan2<<<2,1024,0,stream>>>(deg_dst, rp_dst, deg_src, rp_src, E);
  xg_fill<<<gLE,256,0,stream>>>(nei, LE, rp_dst, cur_dst, col_dst, rp_src, cur_src, col_src);

  xg_gemm<PRE_SCALE_ROW,POST_BIAS,false><<<gg,256,0,stream>>>(
      eattr,169,169, W_mat,128,128, h_pre,128, env_a,nullptr,nullptr, b_mat,
      nullptr,nullptr,nullptr, E);
  xg_gemm<PRE_SILU,POST_X0,false><<<gg,256,0,stream>>>(
      h_pre,128,128, W_emb,128,128, x0,128, nullptr,nullptr,nullptr, b_emb,
      l8,Wvs,nullptr, E);

  for (int l=0;l<3;l++) {
    // m = silu(rbf@Wr_l) * x_l  (fused gate+mul)
    xg_gemm<PRE_NONE,POST_GATE,false><<<gg,256,0,stream>>>(
        rbf,20,20, Wr+(size_t)l*2560,128,128, bufA,128,
        nullptr,nullptr, xsm[l], nullptr,nullptr,nullptr,nullptr, E);
    xg_gather1<<<gW8,256,0,stream>>>(bufA, rp_dst, col_dst, bufB, E);
    xg_gemm<PRE_NONE,POST_CONV,false><<<gg,256,0,stream>>>(
        bufB,128,128, Wx+(size_t)l*16384,128,128, apres[l],128,
        nullptr,nullptr, xsm[l], nullptr,nullptr,nullptr, xsm[l+1], E);
  }

  xg_out<<<512,256,0,stream>>>(bufA, env_a, w_out, eidx, abatch, g_env, results, E);

  // backward (bufA free after xg_out)
  xg_gxinit<<<(int)(((size_t)E*128+255)/256),256,0,stream>>>(env_a, w_out, g_x, E);
  for (int l=2;l>=0;l--) {
    xg_gemm<PRE_MUL_SILUD,POST_PLAIN,true><<<gg,256,0,stream>>>(
        g_x,128,128, Wx+(size_t)l*16384,128,128, bufB,128,
        nullptr, apres[l], nullptr, nullptr,nullptr,nullptr,nullptr, E);
    xg_gather1<<<gW8,256,0,stream>>>(bufB, rp_src, col_src, bufA, E);
    xg_convstream<<<gW4,256,0,stream>>>(bufA, nullptr, nullptr, xsm[l], g_x,
                                        rbf, g_rbf, Wr+(size_t)l*2560, E);
  }
  xg_vpath<<<gW,256,0,stream>>>(g_x, l8, Wvs, g_l8, E);
  xg_gemm<PRE_NONE,POST_MUL_SILUD,true><<<gg,256,0,stream>>>(
      g_x,128,128, W_emb,128,128, bufB,128, nullptr,nullptr, h_pre,
      nullptr,nullptr,nullptr,nullptr, E);
  dim3 g8((E+63)/64, 2);
  xg_gemm<PRE_NONE,POST_PLAIN,true><<<g8,256,0,stream>>>(
      bufB,128,128, W_mat,128,169, vecb,172,
      nullptr,nullptr,nullptr,nullptr,nullptr,nullptr,nullptr, E);
  xg_eattrbwd<<<gW,256,0,stream>>>(vecb, eattr, eagr, env_a, g_env, eg, E);
  xg_force<<<gE,256,0,stream>>>(bv, d_a, g_env, g_rbf, g_l8, eg, eidx, force, E);
}

// Round 6
// 2794.397 us; speedup vs baseline: 1.2692x; 1.2076x over previous
//
#include <hip/hip_runtime.h>
#include <cstdint>

// Round 9: GEMM rebuilt as 128x128 tile (8x8 acc/thread) with float4 staging.
// R5 profile: all top-5 = xg_gemm @202us, VALU 29%, HBM 7%, occ 31% -> GEMM is
// 67% of runtime at 13% of fp32 peak; staging was 24 scalar loads + bounds
// checks per 1024 FMA. Now: 8 float4 VMEM per 2048 FMA, float4 LDS reads,
// 2x FMAs per barrier. Slow guarded path for ldA%4!=0 (eattr) / partial K
// (gate K=20, eattr tail). Epilogues reworked for 8-col layout; math unchanged.
// Gathers/convstream unchanged from R8.

#define CUTOFF 5.0f
#define PI_F 3.14159265358979323846f

__device__ __forceinline__ float siluf(float v){ float s=1.f/(1.f+__expf(-v)); return v*s; }
__device__ __forceinline__ float silud(float v){ float s=1.f/(1.f+__expf(-v)); return s*(1.f+v*(1.f-s)); }

// ---- DPP wave64 sum: result valid in lane 63 (VALU pipe, no LDS traffic)
template<int CTRL>
__device__ __forceinline__ float dpp_radd(float x){
  int y = __builtin_amdgcn_update_dpp(0, __float_as_int(x), CTRL, 0xf, 0xf, false);
  return x + __int_as_float(y);
}
__device__ __forceinline__ float wave_sum63(float x){
  x = dpp_radd<0x111>(x);  // row_shr:1
  x = dpp_radd<0x112>(x);  // row_shr:2
  x = dpp_radd<0x114>(x);  // row_shr:4
  x = dpp_radd<0x118>(x);  // row_shr:8
  x = dpp_radd<0x142>(x);  // row_bcast:15
  x = dpp_radd<0x143>(x);  // row_bcast:31 -> lane63 has full sum
  return x;
}

constexpr int PRE_NONE=0, PRE_SCALE_ROW=1, PRE_SILU=2, PRE_MUL_SILUD=3;
constexpr int POST_PLAIN=0, POST_BIAS=1, POST_GATE=2, POST_X0=3, POST_CONV=4, POST_MUL_SILUD=5;

// ---------------------------------------------------------------- GEMM
// 128x128 tile, 256 threads as 16x16 grid, 8 rows x 8 cols per thread.
template<int PRE, int POST, bool BT>
__global__ __launch_bounds__(256) void xg_gemm(
    const float* __restrict__ A, int ldA, int K,
    const float* __restrict__ B, int ldB, int N,
    float* __restrict__ C, int ldC,
    const float* __restrict__ rowscale,   // PRE_SCALE_ROW
    const float* __restrict__ auxA,       // PRE_MUL_SILUD  (ld 128)
    const float* __restrict__ auxC,       // POST_CONV / POST_GATE (x_l) / POST_MUL_SILUD (h_pre)
    const float* __restrict__ bias,       // POST_BIAS / POST_X0
    const float* __restrict__ l8g,        // POST_X0 (E x 8 row-major)
    const float* __restrict__ Wvsg,       // POST_X0 (8 x 128)
    float* __restrict__ C2,               // POST_CONV x_{l+1}
    int E)
{
  __shared__ float Alds[128][36];         // 144B row stride, 16B aligned
  __shared__ float Blds[32][132];
  __shared__ float l8s[8][128];
  __shared__ float WvsS[8][128];

  const int tid = threadIdx.x;
  const int e0 = blockIdx.x*128;
  const int n0 = blockIdx.y*128;

  if constexpr (POST==POST_X0) {
    for (int i=tid;i<1024;i+=256) WvsS[i>>7][i&127] = Wvsg[i];
    for (int i=tid;i<1024;i+=256) {
      int r=i>>3, c=i&7; int e=e0+r;
      l8s[c][r] = (e<E)? l8g[(size_t)e*8+c] : 0.f;
    }
  }

  const int tr = tid>>4, tc = tid&15;
  float acc[8][8];
  #pragma unroll
  for (int i=0;i<8;i++)
    #pragma unroll
    for (int j=0;j<8;j++) acc[i][j]=0.f;

  const bool alignedA = ((ldA&3)==0);

  for (int k0=0;k0<K;k0+=32) {
    __syncthreads();
    const bool fullK = (k0+32<=K);
    { // ---- A tile 128x32: thread (ra=tid>>1, ha=tid&1) loads 4 float4
      const int ra = tid>>1, ha = tid&1;
      const int e = e0+ra;
      float rsc = 1.f;
      if constexpr (PRE==PRE_SCALE_ROW) rsc = (e<E)? rowscale[e] : 0.f;
      #pragma unroll
      for (int q=0;q<4;q++){
        const int kk = ha*16+q*4, k = k0+kk;
        float4 v = make_float4(0.f,0.f,0.f,0.f);
        if (e<E) {
          if (fullK && alignedA) {
            v = *(const float4*)&A[(size_t)e*ldA + k];
          } else {
            if (k+0<K) v.x = A[(size_t)e*ldA + k+0];
            if (k+1<K) v.y = A[(size_t)e*ldA + k+1];
            if (k+2<K) v.z = A[(size_t)e*ldA + k+2];
            if (k+3<K) v.w = A[(size_t)e*ldA + k+3];
          }
          if constexpr (PRE==PRE_SCALE_ROW) { v.x*=rsc; v.y*=rsc; v.z*=rsc; v.w*=rsc; }
          if constexpr (PRE==PRE_SILU) { v.x=siluf(v.x); v.y=siluf(v.y); v.z=siluf(v.z); v.w=siluf(v.w); }
          if constexpr (PRE==PRE_MUL_SILUD) {
            float4 ax = *(const float4*)&auxA[(size_t)e*128 + k];
            v.x*=silud(ax.x); v.y*=silud(ax.y); v.z*=silud(ax.z); v.w*=silud(ax.w);
          }
        }
        *(float4*)&Alds[ra][kk] = v;
      }
    }
    if constexpr (!BT) { // B row-major KxN (all !BT uses have N=128, n0=0)
      const int kb = tid>>3, ng = (tid&7)*16;
      const int k = k0+kb;
      #pragma unroll
      for (int q=0;q<4;q++){
        float4 v = make_float4(0.f,0.f,0.f,0.f);
        if (k<K) v = *(const float4*)&B[(size_t)k*ldB + n0 + ng + q*4];
        *(float4*)&Blds[kb][ng+q*4] = v;
      }
    } else {             // B = W^T, W row-major NxK (ldB, always %4==0)
      const int nb = tid>>1, hb = tid&1;
      const int nn = n0+nb;
      #pragma unroll
      for (int q=0;q<4;q++){
        const int kk = hb*16+q*4, k = k0+kk;
        float4 v = make_float4(0.f,0.f,0.f,0.f);
        if (nn<N) {
          if (k+3<K) v = *(const float4*)&B[(size_t)nn*ldB + k];
          else {
            if (k+0<K) v.x = B[(size_t)nn*ldB + k+0];
            if (k+1<K) v.y = B[(size_t)nn*ldB + k+1];
            if (k+2<K) v.z = B[(size_t)nn*ldB + k+2];
            if (k+3<K) v.w = B[(size_t)nn*ldB + k+3];
          }
        }
        Blds[kk+0][nb]=v.x; Blds[kk+1][nb]=v.y; Blds[kk+2][nb]=v.z; Blds[kk+3][nb]=v.w;
      }
    }
    __syncthreads();
    #pragma unroll
    for (int kk4=0;kk4<8;kk4++) {
      float bb[4][8];
      #pragma unroll
      for (int q=0;q<4;q++){
        float4 x = *(const float4*)&Blds[kk4*4+q][tc*8];
        float4 y = *(const float4*)&Blds[kk4*4+q][tc*8+4];
        bb[q][0]=x.x; bb[q][1]=x.y; bb[q][2]=x.z; bb[q][3]=x.w;
        bb[q][4]=y.x; bb[q][5]=y.y; bb[q][6]=y.z; bb[q][7]=y.w;
      }
      #pragma unroll
      for (int i=0;i<8;i++) {
        float4 a = *(const float4*)&Alds[tr*8+i][kk4*4];
        float av[4]={a.x,a.y,a.z,a.w};
        #pragma unroll
        for (int q=0;q<4;q++)
          #pragma unroll
          for (int j=0;j<8;j++)
            acc[i][j] = fmaf(av[q], bb[q][j], acc[i][j]);
      }
    }
  }

  const int cb = n0 + tc*8;
  #pragma unroll
  for (int i=0;i<8;i++) {
    int e = e0 + tr*8 + i;
    if (e>=E) break;
    size_t ci = (size_t)e*ldC + cb;
    float4 lo = make_float4(acc[i][0],acc[i][1],acc[i][2],acc[i][3]);
    float4 hi = make_float4(acc[i][4],acc[i][5],acc[i][6],acc[i][7]);
    if constexpr (POST==POST_BIAS) {
      float4 b0 = *(const float4*)&bias[cb];
      float4 b1 = *(const float4*)&bias[cb+4];
      lo.x+=b0.x; lo.y+=b0.y; lo.z+=b0.z; lo.w+=b0.w;
      hi.x+=b1.x; hi.y+=b1.y; hi.z+=b1.z; hi.w+=b1.w;
      *(float4*)&C[ci]=lo; *(float4*)&C[ci+4]=hi;
    } else if constexpr (POST==POST_GATE) { // m = silu(acc) * x_l
      float4 x0v = *(const float4*)&auxC[(size_t)e*128 + cb];
      float4 x1v = *(const float4*)&auxC[(size_t)e*128 + cb+4];
      lo.x=siluf(lo.x)*x0v.x; lo.y=siluf(lo.y)*x0v.y; lo.z=siluf(lo.z)*x0v.z; lo.w=siluf(lo.w)*x0v.w;
      hi.x=siluf(hi.x)*x1v.x; hi.y=siluf(hi.y)*x1v.y; hi.z=siluf(hi.z)*x1v.z; hi.w=siluf(hi.w)*x1v.w;
      *(float4*)&C[ci]=lo; *(float4*)&C[ci+4]=hi;
    } else if constexpr (POST==POST_X0) {
      int r = tr*8+i;
      float vp[8];
      #pragma unroll
      for (int j=0;j<8;j++) vp[j]=0.f;
      #pragma unroll
      for (int c=0;c<8;c++){
        float lc = l8s[c][r];
        float4 w0 = *(const float4*)&WvsS[c][cb];
        float4 w1 = *(const float4*)&WvsS[c][cb+4];
        vp[0]=fmaf(lc,w0.x,vp[0]); vp[1]=fmaf(lc,w0.y,vp[1]);
        vp[2]=fmaf(lc,w0.z,vp[2]); vp[3]=fmaf(lc,w0.w,vp[3]);
        vp[4]=fmaf(lc,w1.x,vp[4]); vp[5]=fmaf(lc,w1.y,vp[5]);
        vp[6]=fmaf(lc,w1.z,vp[6]); vp[7]=fmaf(lc,w1.w,vp[7]);
      }
      float4 b0 = *(const float4*)&bias[cb];
      float4 b1 = *(const float4*)&bias[cb+4];
      lo.x += b0.x + siluf(vp[0]); lo.y += b0.y + siluf(vp[1]);
      lo.z += b0.z + siluf(vp[2]); lo.w += b0.w + siluf(vp[3]);
      hi.x += b1.x + siluf(vp[4]); hi.y += b1.y + siluf(vp[5]);
      hi.z += b1.z + siluf(vp[6]); hi.w += b1.w + siluf(vp[7]);
      *(float4*)&C[ci]=lo; *(float4*)&C[ci+4]=hi;
    } else if constexpr (POST==POST_CONV) {
      *(float4*)&C[ci]=lo; *(float4*)&C[ci+4]=hi;          // apre_l
      float4 x0v = *(const float4*)&auxC[(size_t)e*128 + cb];
      float4 x1v = *(const float4*)&auxC[(size_t)e*128 + cb+4];
      float4 o0 = make_float4(x0v.x+siluf(lo.x), x0v.y+siluf(lo.y),
                              x0v.z+siluf(lo.z), x0v.w+siluf(lo.w));
      float4 o1 = make_float4(x1v.x+siluf(hi.x), x1v.y+siluf(hi.y),
                              x1v.z+siluf(hi.z), x1v.w+siluf(hi.w));
      *(float4*)&C2[ci]=o0; *(float4*)&C2[ci+4]=o1;        // x_{l+1}
    } else if constexpr (POST==POST_MUL_SILUD) {
      float4 a0 = *(const float4*)&auxC[(size_t)e*128 + cb];
      float4 a1 = *(const float4*)&auxC[(size_t)e*128 + cb+4];
      lo.x*=silud(a0.x); lo.y*=silud(a0.y); lo.z*=silud(a0.z); lo.w*=silud(a0.w);
      hi.x*=silud(a1.x); hi.y*=silud(a1.y); hi.z*=silud(a1.z); hi.w*=silud(a1.w);
      *(float4*)&C[ci]=lo; *(float4*)&C[ci+4]=hi;
    } else { // POST_PLAIN (N may be 169)
      if (cb+7 < N) { *(float4*)&C[ci]=lo; *(float4*)&C[ci+4]=hi; }
      else {
        float vv[8]={lo.x,lo.y,lo.z,lo.w,hi.x,hi.y,hi.z,hi.w};
        #pragma unroll
        for (int j=0;j<8;j++) if (cb+j<N) C[ci+j]=vv[j];
      }
    }
  }
}

// ---------------------------------------------------------------- geometry
__global__ __launch_bounds__(256) void xg_geom(const float* __restrict__ pos,
  const int* __restrict__ eidx, int E,
  float* __restrict__ bv, float* __restrict__ d_a, float* __restrict__ env_a,
  float* __restrict__ l8, float* __restrict__ rbf)
{
  int e = blockIdx.x*256+threadIdx.x;
  if (e>=E) return;
  int s = eidx[e], t = eidx[E+e];
  float bx = pos[s*3+0]-pos[t*3+0];
  float by = pos[s*3+1]-pos[t*3+1];
  float bz = pos[s*3+2]-pos[t*3+2];
  float d = sqrtf(bx*bx+by*by+bz*bz + 1e-12f);
  bv[(size_t)e*3+0]=bx; bv[(size_t)e*3+1]=by; bv[(size_t)e*3+2]=bz;
  d_a[e]=d;
  float xx = d/CUTOFF;
  float x2=xx*xx, x4=x2*x2, x5=x4*xx, x6=x5*xx, x7=x6*xx;
  env_a[e] = (d<CUTOFF)? (1.f-21.f*x5+35.f*x6-15.f*x7) : 0.f;
  float inv = 1.f/d;
  float ux=bx*inv, uy=by*inv, uz=bz*inv;
  const float s3 = 1.7320508075688772f;
  size_t b8=(size_t)e*8;
  l8[b8+0]=uy; l8[b8+1]=uz; l8[b8+2]=ux;
  l8[b8+3]=s3*ux*uy; l8[b8+4]=s3*uy*uz;
  l8[b8+5]=0.5f*(3.f*uz*uz-1.f);
  l8[b8+6]=s3*ux*uz; l8[b8+7]=0.5f*s3*(ux*ux-uy*uy);
  float ds = fmaxf(d, 1e-6f);
  const float cc = 0.632455532033676f; // sqrt(2/5)
  #pragma unroll
  for (int k=0;k<20;k++){
    float th = ((k+1)*PI_F)*ds/CUTOFF;
    rbf[(size_t)e*20+k] = cc*sinf(th)/ds;
  }
}

// tile-summed Wv: Wvs[8][128]
__global__ void xg_wvs(const float* __restrict__ Wv, float* __restrict__ Wvs){
  int h=threadIdx.x;
  #pragma unroll
  for (int c=0;c<3;c++){
    float s=0.f;
    for (int t=0;t<64;t++) s+=Wv[(size_t)(t*3+c)*128+h];
    Wvs[c*128+h]=s;
  }
  #pragma unroll
  for (int c=0;c<5;c++){
    float s=0.f;
    for (int t=0;t<32;t++) s+=Wv[(size_t)(192+t*5+c)*128+h];
    Wvs[(3+c)*128+h]=s;
  }
}

// ---------------------------------------------------------------- CSR build
__global__ __launch_bounds__(256) void xg_hist(const int* __restrict__ nei, int LE,
                                               int* deg_dst, int* deg_src){
  int i=blockIdx.x*256+threadIdx.x;
  if (i>=LE) return;
  atomicAdd(&deg_src[nei[i]],1);
  atomicAdd(&deg_dst[nei[LE+i]],1);
}

__global__ __launch_bounds__(1024) void xg_scan2(const int* __restrict__ degA, int* __restrict__ rpA,
                                                 const int* __restrict__ degB, int* __restrict__ rpB, int n){
  const int* deg = (blockIdx.x==0)? degA : degB;
  int* rp = (blockIdx.x==0)? rpA : rpB;
  __shared__ int wsum[16];
  int tid=threadIdx.x, lane=tid&63, wid=tid>>6;
  int carry=0;
  for (int base=0;base<n;base+=1024){
    int i=base+tid;
    int v=(i<n)?deg[i]:0;
    int x=v;
    #pragma unroll
    for (int off=1;off<64;off<<=1){int y=__shfl_up(x,off); if(lane>=off)x+=y;}
    if (lane==63) wsum[wid]=x;
    __syncthreads();
    if (wid==0 && lane<16){
      int s=wsum[lane];
      #pragma unroll
      for (int off=1;off<16;off<<=1){int y=__shfl_up(s,off); if(lane>=off)s+=y;}
      wsum[lane]=s;
    }
    __syncthreads();
    int woff=(wid==0)?0:wsum[wid-1];
    if (i<n) rp[i]=carry+woff+x-v;
    carry+=wsum[15];
    __syncthreads();
  }
  if (tid==0) rp[n]=carry;
}

__global__ __launch_bounds__(256) void xg_fill(const int* __restrict__ nei, int LE,
    const int* __restrict__ rp_dst, int* cur_dst, int* col_dst,
    const int* __restrict__ rp_src, int* cur_src, int* col_src){
  int i=blockIdx.x*256+threadIdx.x;
  if (i>=LE) return;
  int s=nei[i], d=nei[LE+i];
  int pd = rp_dst[d] + atomicAdd(&cur_dst[d],1);
  col_dst[pd] = s;  // store le_src for fwd gather
  int ps = rp_src[s] + atomicAdd(&cur_src[s],1);
  col_src[ps] = d;  // store le_dst for bwd gather
}

// ---------------------------------------------------------------- gathers
// gather1: 8 rows per wave, float2 lanes, branchless predication,
// next-iter col[] indices prefetched ahead of FMA consume.
__global__ __launch_bounds__(256) void xg_gather1(const float* __restrict__ g,
  const int* __restrict__ rp, const int* __restrict__ col,
  float* __restrict__ out, int E)
{
  const float2* g2 = (const float2*)g;
  float2* out2 = (float2*)out;
  int w=(blockIdx.x*256+threadIdx.x)>>6, lane=threadIdx.x&63;
  int r0 = w*8;
  if (r0>=E) return;
  int s[8], e[8];
  #pragma unroll
  for (int j=0;j<8;j++){
    int r=r0+j;
    s[j]=(r<E)?rp[r]:0; e[j]=(r<E)?rp[r+1]:0;
  }
  float2 acc[8];
  #pragma unroll
  for (int j=0;j<8;j++) acc[j]=make_float2(0.f,0.f);

  int c[8]; float m[8];
  int live=0;
  #pragma unroll
  for (int j=0;j<8;j++){
    bool a = s[j]<e[j]; live |= (int)a;
    c[j]=a?col[s[j]]:0; m[j]=a?1.f:0.f;
  }
  while (live){
    float2 v[8];
    #pragma unroll
    for (int j=0;j<8;j++) v[j]=g2[(size_t)c[j]*64+lane];
    // prefetch next-iter indices while v loads are in flight
    int cn[8]; float mn[8];
    live=0;
    #pragma unroll
    for (int j=0;j<8;j++){
      s[j]++;
      bool a = s[j]<e[j]; live |= (int)a;
      cn[j]=a?col[s[j]]:0; mn[j]=a?1.f:0.f;
    }
    #pragma unroll
    for (int j=0;j<8;j++){
      acc[j].x=fmaf(v[j].x,m[j],acc[j].x); acc[j].y=fmaf(v[j].y,m[j],acc[j].y);
      c[j]=cn[j]; m[j]=mn[j];
    }
  }
  #pragma unroll
  for (int j=0;j<8;j++){
    int r=r0+j;
    if (r<E) out2[(size_t)r*64+lane]=acc[j];
  }
}

// streaming conv-bwd epilogue: G (gathered, coalesced), gate/gpre recomputed;
// g_x += gate*G; g_rbf[e][k] = sum_h (x_l*G*silu'(gpre))[h]*Wr[k][h] via DPP.
__global__ __launch_bounds__(256) void xg_convstream(const float* __restrict__ G,
  const int* /*unused*/, const int* /*unused2*/,
  const float* __restrict__ xl, float* __restrict__ g_x,
  const float* __restrict__ rbf, float* __restrict__ g_rbf,
  const float* __restrict__ Wr_l, int E)
{
  __shared__ float wr[2560];
  for (int i=threadIdx.x;i<2560;i+=256) wr[i]=Wr_l[i];
  __syncthreads();
  const float2* G2 = (const float2*)G;
  const float2* xl2 = (const float2*)xl;
  float2* gx2 = (float2*)g_x;
  const float2* wr2 = (const float2*)wr;
  int w=(blockIdx.x*256+threadIdx.x)>>6, lane=threadIdx.x&63;
  int r0 = w*4;
  if (r0>=E) return;
  #pragma unroll
  for (int j=0;j<4;j++){
    int row=r0+j;
    if (row>=E) break;
    size_t b=(size_t)row*64+lane;
    float2 a = G2[b];          // streaming, coalesced
    float2 x2v = xl2[b];
    float rk[20];
    #pragma unroll
    for (int k=0;k<20;k++) rk[k]=rbf[(size_t)row*20+k];
    float gp0=0.f,gp1=0.f;
    #pragma unroll
    for (int k=0;k<20;k++){
      float2 w2=wr2[k*64+lane];
      gp0=fmaf(rk[k],w2.x,gp0); gp1=fmaf(rk[k],w2.y,gp1);
    }
    float ss0=1.f/(1.f+__expf(-gp0)), ss1=1.f/(1.f+__expf(-gp1));
    float gate0=gp0*ss0, gate1=gp1*ss1;
    float sd0=ss0*(1.f+gp0*(1.f-ss0)), sd1=ss1*(1.f+gp1*(1.f-ss1));
    float gg0 = x2v.x*a.x*sd0, gg1 = x2v.y*a.y*sd1;
    float2 gx = gx2[b];
    gx.x += gate0*a.x; gx.y += gate1*a.y;
    gx2[b] = gx;
    #pragma unroll
    for (int k=0;k<20;k++){
      float2 w2=wr2[k*64+lane];
      float v = wave_sum63(fmaf(gg0, w2.x, gg1*w2.y));
      if (lane==63) g_rbf[(size_t)row*20+k] += v;
    }
  }
}

// ---------------------------------------------------------------- outputs
__global__ __launch_bounds__(256) void xg_out(const float* __restrict__ x3,
  const float* __restrict__ env_a, const float* __restrict__ w_out,
  const int* __restrict__ eidx, const int* __restrict__ abatch,
  float* __restrict__ g_env, float* __restrict__ results, int E)
{
  __shared__ float bins[64];
  __shared__ float wsh[128];
  int tid=threadIdx.x;
  if (tid<64) bins[tid]=0.f;
  if (tid<128) wsh[tid]=w_out[tid];
  __syncthreads();
  int lane=tid&63;
  int gw = blockIdx.x*4 + (tid>>6);
  int stride = gridDim.x*4;
  for (int e=gw; e<E; e+=stride){
    size_t b=(size_t)e*128;
    float v = wave_sum63(x3[b+lane]*wsh[lane] + x3[b+lane+64]*wsh[lane+64]);
    if (lane==63){
      g_env[e]=v;
      float ee=v*env_a[e];
      if (ee!=0.f) atomicAdd(&bins[abatch[eidx[e]]], ee);
    }
  }
  __syncthreads();
  if (tid<64){ float bb=bins[tid]; if (bb!=0.f) atomicAdd(&results[tid], bb); }
}

__global__ __launch_bounds__(256) void xg_gxinit(const float* __restrict__ env_a,
  const float* __restrict__ w_out, float* __restrict__ g_x, int E){
  size_t i = (size_t)blockIdx.x*256+threadIdx.x;
  if (i >= (size_t)E*128) return;
  int e = (int)(i>>7), h = (int)(i&127);
  g_x[i] = env_a[e]*w_out[h];
}

// rsh path bwd: g_l8[c] = sum_h g_x0[h]*silu'(vpre[h])*Wvs[c][h]
__global__ __launch_bounds__(256) void xg_vpath(const float* __restrict__ g_x,
  const float* __restrict__ l8, const float* __restrict__ Wvs,
  float* __restrict__ g_l8, int E)
{
  __shared__ float W[1024];
  for (int i=threadIdx.x;i<1024;i+=256) W[i]=Wvs[i];
  __syncthreads();
  int gw=(blockIdx.x*256+threadIdx.x)>>6, lane=threadIdx.x&63;
  if (gw>=E) return;
  float l[8];
  #pragma unroll
  for (int c=0;c<8;c++) l[c]=l8[(size_t)gw*8+c];
  float vp0=0.f, vp1=0.f;
  #pragma unroll
  for (int c=0;c<8;c++){ vp0=fmaf(l[c],W[c*128+lane],vp0); vp1=fmaf(l[c],W[c*128+lane+64],vp1); }
  size_t b=(size_t)gw*128;
  float gv0 = g_x[b+lane]*silud(vp0);
  float gv1 = g_x[b+lane+64]*silud(vp1);
  #pragma unroll
  for (int c=0;c<8;c++){
    float v = wave_sum63(fmaf(gv0, W[c*128+lane], gv1*W[c*128+lane+64]));
    if (lane==63) g_l8[(size_t)gw*8+c] = v;
  }
}

// eattr path: g_env += vec.eattr; edge_grads[k] = env * vec . eagrad[:,k,:]
__global__ __launch_bounds__(256) void xg_eattrbwd(const float* __restrict__ vecb,
  const float* __restrict__ eattr, const float* __restrict__ eagr,
  const float* __restrict__ env_a, float* __restrict__ g_env,
  float* __restrict__ eg, int E)
{
  int gw=(blockIdx.x*256+threadIdx.x)>>6, lane=threadIdx.x&63;
  if (gw>=E) return;
  const float* vr = vecb + (size_t)gw*172;
  const float* ar = eattr + (size_t)gw*169;
  const float* gr = eagr + (size_t)gw*507;
  float se=0.f,e0=0.f,e1=0.f,e2=0.f;
  for (int f=lane; f<169; f+=64){
    float v=vr[f];
    se=fmaf(v,ar[f],se);
    e0=fmaf(v,gr[f],e0);
    e1=fmaf(v,gr[169+f],e1);
    e2=fmaf(v,gr[338+f],e2);
  }
  se=wave_sum63(se); e0=wave_sum63(e0); e1=wave_sum63(e1); e2=wave_sum63(e2);
  if (lane==63){
    g_env[gw] += se;
    float en = env_a[gw];
    eg[(size_t)gw*3+0]=e0*en; eg[(size_t)gw*3+1]=e1*en; eg[(size_t)gw*3+2]=e2*en;
  }
}

// final: g_d (env + rbf paths), g_u -> g_bv, + edge_grads, scatter to force
__global__ __launch_bounds__(256) void xg_force(const float* __restrict__ bv,
  const float* __restrict__ d_a, const float* __restrict__ g_env,
  const float* __restrict__ g_rbf, const float* __restrict__ g_l8,
  const float* __restrict__ eg, const int* __restrict__ eidx,
  float* __restrict__ force, int E)
{
  int e = blockIdx.x*256+threadIdx.x;
  if (e>=E) return;
  float d = d_a[e];
  float inv = 1.f/d;
  float xx = d/CUTOFF;
  float x2=xx*xx, x4=x2*x2, x5=x4*xx, x6=x5*xx;
  float g_d = g_env[e] * ((d<CUTOFF)? ((-105.f*x4+210.f*x5-105.f*x6)/CUTOFF) : 0.f);
  const float cc=0.632455532033676f;
  float tie = (d>1e-6f)?1.f:0.5f;
  float acc=0.f;
  #pragma unroll
  for (int k=0;k<20;k++){
    float a=(k+1)*PI_F;
    float th=a*d/CUTOFF;
    float sn=sinf(th), cs=cosf(th);
    float drb = cc*((a/CUTOFF)*cs*d - sn)*inv*inv;
    acc = fmaf(g_rbf[(size_t)e*20+k], drb, acc);
  }
  g_d += acc*tie;
  size_t b3=(size_t)e*3, b8=(size_t)e*8;
  float ux=bv[b3+0]*inv, uy=bv[b3+1]*inv, uz=bv[b3+2]*inv;
  const float s3=1.7320508075688772f;
  float G1y=g_l8[b8+0], G1z=g_l8[b8+1], G1x=g_l8[b8+2];
  float A=g_l8[b8+3], B=g_l8[b8+4], Cq=g_l8[b8+5], D=g_l8[b8+6], F=g_l8[b8+7];
  float gux = G1x + s3*(uy*A + uz*D + ux*F);
  float guy = G1y + s3*(ux*A + uz*B) - s3*uy*F;
  float guz = G1z + s3*uy*B + 3.f*uz*Cq + s3*ux*D;
  float ud = ux*gux+uy*guy+uz*guz;
  float gbx = (gux-ux*ud)*inv + g_d*ux;
  float gby = (guy-uy*ud)*inv + g_d*uy;
  float gbz = (guz-uz*ud)*inv + g_d*uz;
  float fx = gbx + eg[b3+0];
  float fy = gby + eg[b3+1];
  float fz = gbz + eg[b3+2];
  int s=eidx[e], t=eidx[E+e];
  atomicAdd(&force[s*3+0],-fx); atomicAdd(&force[s*3+1],-fy); atomicAdd(&force[s*3+2],-fz);
  atomicAdd(&force[t*3+0], fx); atomicAdd(&force[t*3+1], fy); atomicAdd(&force[t*3+2], fz);
}

// ================================================================ launch
extern "C" void kernel_launch(void* const* d_in, const int* in_sizes, int n_in,
                              void* d_out, int out_size, void* d_ws, size_t ws_size,
                              hipStream_t stream)
{
  const float* pos   = (const float*)d_in[0];
  const float* eattr = (const float*)d_in[1];
  const float* eagr  = (const float*)d_in[2];
  const float* W_mat = (const float*)d_in[3];
  const float* b_mat = (const float*)d_in[4];
  const float* W_emb = (const float*)d_in[5];
  const float* b_emb = (const float*)d_in[6];
  const float* Wv    = (const float*)d_in[7];
  const float* Wr    = (const float*)d_in[8];
  const float* Wx    = (const float*)d_in[9];
  const float* w_out = (const float*)d_in[10];
  const int* eidx    = (const int*)d_in[11];
  const int* nei     = (const int*)d_in[12];
  const int* abatch  = (const int*)d_in[13];

  const int E  = in_sizes[1]/169;
  const int LE = in_sizes[12]/2;

  float* p = (float*)d_ws;
  auto alloc=[&](size_t n){ float* q=p; p+=n; return q; };
  float* bv    = alloc((size_t)3*E);
  float* d_a   = alloc(E);
  float* env_a = alloc(E);
  float* l8    = alloc((size_t)8*E);
  float* rbf   = alloc((size_t)20*E);
  float* g_env = alloc(E);
  float* g_l8  = alloc((size_t)8*E);
  float* eg    = alloc((size_t)3*E);
  float* Wvs   = alloc(1024);
  float* h_pre = alloc((size_t)128*E);
  float* x0    = alloc((size_t)128*E);
  float* x1    = alloc((size_t)128*E);
  float* x2    = alloc((size_t)128*E);
  float* apre0 = alloc((size_t)128*E);
  float* apre1 = alloc((size_t)128*E);
  float* apre2 = alloc((size_t)128*E);
  float* bufA  = alloc((size_t)128*E);   // m / x3 / G (bwd gather target)
  float* bufB  = alloc((size_t)128*E);   // agg / g_agg / g_hpre
  float* g_x   = alloc((size_t)128*E);
  float* g_rbf = alloc((size_t)20*E);    // zero-region start
  int* ip = (int*)p;
  int* deg_dst = ip; ip+=E;
  int* deg_src = ip; ip+=E;
  int* cur_dst = ip; ip+=E;
  int* cur_src = ip; ip+=E;              // zero-region end (24E * 4B)
  int* rp_dst  = ip; ip+=E+1;
  int* rp_src  = ip; ip+=E+1;
  int* col_dst = ip; ip+=LE;
  int* col_src = ip; ip+=LE;
  float* vecb  = apre0;                  // (E x 169, ld 172) aliases apre0/1

  float* results = (float*)d_out;
  float* force   = results + 64;

  hipMemsetAsync(d_out, 0, (size_t)out_size*sizeof(float), stream);
  hipMemsetAsync(g_rbf, 0, (size_t)24*E*sizeof(float), stream);

  float* xsm[4]   = {x0,x1,x2,bufA};
  float* apres[3] = {apre0,apre1,apre2};

  const int gE  = (E+255)/256;
  const int gLE = (LE+255)/256;
  const int gW  = (E+3)/4;          // one wave per edge (1-row kernels)
  const int gW4 = (E+15)/16;        // 4 waves x 4 rows per block (convstream)
  const int gW8 = (E+31)/32;        // 4 waves x 8 rows per block (gather1)
  dim3 gg((E+127)/128, 1);          // 128-row GEMM tiles

  // forward
  xg_geom<<<gE,256,0,stream>>>(pos, eidx, E, bv, d_a, env_a, l8, rbf);
  xg_wvs<<<1,128,0,stream>>>(Wv, Wvs);
  xg_hist<<<gLE,256,0,stream>>>(nei, LE, deg_dst, deg_src);
  xg_scan2<<<2,1024,0,stream>>>(deg_dst, rp_dst, deg_src, rp_src, E);
  xg_fill<<<gLE,256,0,stream>>>(nei, LE, rp_dst, cur_dst, col_dst, rp_src, cur_src, col_src);

  xg_gemm<PRE_SCALE_ROW,POST_BIAS,false><<<gg,256,0,stream>>>(
      eattr,169,169, W_mat,128,128, h_pre,128, env_a,nullptr,nullptr, b_mat,
      nullptr,nullptr,nullptr, E);
  xg_gemm<PRE_SILU,POST_X0,false><<<gg,256,0,stream>>>(
      h_pre,128,128, W_emb,128,128, x0,128, nullptr,nullptr,nullptr, b_emb,
      l8,Wvs,nullptr, E);

  for (int l=0;l<3;l++) {
    // m = silu(rbf@Wr_l) * x_l  (fused gate+mul)
    xg_gemm<PRE_NONE,POST_GATE,false><<<gg,256,0,stream>>>(
        rbf,20,20, Wr+(size_t)l*2560,128,128, bufA,128,
        nullptr,nullptr, xsm[l], nullptr,nullptr,nullptr,nullptr, E);
    xg_gather1<<<gW8,256,0,stream>>>(bufA, rp_dst, col_dst, bufB, E);
    xg_gemm<PRE_NONE,POST_CONV,false><<<gg,256,0,stream>>>(
        bufB,128,128, Wx+(size_t)l*16384,128,128, apres[l],128,
        nullptr,nullptr, xsm[l], nullptr,nullptr,nullptr, xsm[l+1], E);
  }

  xg_out<<<512,256,0,stream>>>(bufA, env_a, w_out, eidx, abatch, g_env, results, E);

  // backward (bufA free after xg_out)
  xg_gxinit<<<(int)(((size_t)E*128+255)/256),256,0,stream>>>(env_a, w_out, g_x, E);
  for (int l=2;l>=0;l--) {
    xg_gemm<PRE_MUL_SILUD,POST_PLAIN,true><<<gg,256,0,stream>>>(
        g_x,128,128, Wx+(size_t)l*16384,128,128, bufB,128,
        nullptr, apres[l], nullptr, nullptr,nullptr,nullptr,nullptr, E);
    xg_gather1<<<gW8,256,0,stream>>>(bufB, rp_src, col_src, bufA, E);
    xg_convstream<<<gW4,256,0,stream>>>(bufA, nullptr, nullptr, xsm[l], g_x,
                                        rbf, g_rbf, Wr+(size_t)l*2560, E);
  }
  xg_vpath<<<gW,256,0,stream>>>(g_x, l8, Wvs, g_l8, E);
  xg_gemm<PRE_NONE,POST_MUL_SILUD,true><<<gg,256,0,stream>>>(
      g_x,128,128, W_emb,128,128, bufB,128, nullptr,nullptr, h_pre,
      nullptr,nullptr,nullptr,nullptr, E);
  dim3 g8((E+127)/128, 2);
  xg_gemm<PRE_NONE,POST_PLAIN,true><<<g8,256,0,stream>>>(
      bufB,128,128, W_mat,128,169, vecb,172,
      nullptr,nullptr,nullptr,nullptr,nullptr,nullptr,nullptr, E);
  xg_eattrbwd<<<gW,256,0,stream>>>(vecb, eattr, eagr, env_a, g_env, eg, E);
  xg_force<<<gE,256,0,stream>>>(bv, d_a, g_env, g_rbf, g_l8, eg, eidx, force, E);
}